// Round 11
// baseline (124.859 us; speedup 1.0000x reference)
//
#include <hip/hip_runtime.h>

// Koopman bilinear rollout: preds[b,t,d] = (z0 @ Kd^{t+1})[b,d], D=B=256, T=512.
// Kd = (I-A)^-1(I+A), A=0.5*dt*K -> order-4 Neumann (2 launches, proven r2-r10).
// E-powers E^2..E^8 in 3 GEMM stages; comb writes all 32 bf16-T M-tables and
// W1/W2/W3=(I+E)^{32,64,96} f32; 3-level checkpoint scan; ONE batched
// bf16-MFMA fill for the remaining 497 timesteps.
// r11: fill retiled 128x128 -> 256x256 (one block per timestep, 8 waves):
// halves table reads (254->127 MB), doubles MFMA-per-barrier, 1KB-row stores.
// DEAD ENDS (do not retry): persistent kernel + grid barrier -- r5 acquire-poll
// 392us, r7 relaxed-poll+fence 289us; cache-maintenance storm either way.
// r10 lesson: chain stages are ~2.5us each; removing launches is exhausted.

#define DD 256
#define TT 512
#define MATF (DD * DD)
#define LDT ((size_t)TT * (size_t)DD)

typedef __attribute__((ext_vector_type(8))) short bf16x8;
typedef __attribute__((ext_vector_type(4))) float f32x4;

#define GLD16(g, l)                                                  \
    __builtin_amdgcn_global_load_lds(                                \
        (const __attribute__((address_space(1))) void*)(g),          \
        (__attribute__((address_space(3))) void*)(l), 16, 0, 0)

static __device__ __forceinline__ unsigned short f2bf(float f) {
    unsigned int u = __float_as_uint(f);
    u += 0x7fffu + ((u >> 16) & 1u);
    return (unsigned short)(u >> 16);
}
static __device__ __forceinline__ unsigned pack2bf(float a, float b) {
    return (unsigned)f2bf(a) | ((unsigned)f2bf(b) << 16);
}

// ---- 32x32-tile f32 GEMM core: 256 threads, K=256, K_BLK=64, reg prefetch ----
__device__ __forceinline__ void g32_core(const float* __restrict__ Ab, int lda,
                                         const float* __restrict__ Bb, int ldb,
                                         int rowBase, int colBase, float acc[2][2]) {
    __shared__ __align__(16) float As[64 * 38];
    __shared__ __align__(16) float Bs[64 * 40];
    const int tid = threadIdx.x;
    const int tx = tid & 15, ty = tid >> 4;
    const int am = tid >> 4;
    const int ak = (tid & 15) << 2;
    const int bk = tid >> 3;
    const int bn = (tid & 7) << 2;

    acc[0][0] = acc[0][1] = acc[1][0] = acc[1][1] = 0.f;

    float4 pa0 = *(const float4*)(Ab + (size_t)(rowBase + am) * lda + ak);
    float4 pa1 = *(const float4*)(Ab + (size_t)(rowBase + am + 16) * lda + ak);
    float4 pb0 = *(const float4*)(Bb + (size_t)bk * ldb + colBase + bn);
    float4 pb1 = *(const float4*)(Bb + (size_t)(bk + 32) * ldb + colBase + bn);

    for (int k0 = 0; k0 < DD; k0 += 64) {
        As[(ak + 0) * 38 + am] = pa0.x;
        As[(ak + 1) * 38 + am] = pa0.y;
        As[(ak + 2) * 38 + am] = pa0.z;
        As[(ak + 3) * 38 + am] = pa0.w;
        As[(ak + 0) * 38 + am + 16] = pa1.x;
        As[(ak + 1) * 38 + am + 16] = pa1.y;
        As[(ak + 2) * 38 + am + 16] = pa1.z;
        As[(ak + 3) * 38 + am + 16] = pa1.w;
        *(float4*)(&Bs[bk * 40 + bn]) = pb0;
        *(float4*)(&Bs[(bk + 32) * 40 + bn]) = pb1;
        __syncthreads();
        if (k0 + 64 < DD) {
            pa0 = *(const float4*)(Ab + (size_t)(rowBase + am) * lda + k0 + 64 + ak);
            pa1 = *(const float4*)(Ab + (size_t)(rowBase + am + 16) * lda + k0 + 64 + ak);
            pb0 = *(const float4*)(Bb + (size_t)(bk + k0 + 64) * ldb + colBase + bn);
            pb1 = *(const float4*)(Bb + (size_t)(bk + 32 + k0 + 64) * ldb + colBase + bn);
        }
#pragma unroll
        for (int kk = 0; kk < 64; ++kk) {
            float2 a2 = *(const float2*)(&As[kk * 38 + (ty << 1)]);
            float2 b2 = *(const float2*)(&Bs[kk * 40 + (tx << 1)]);
            acc[0][0] = fmaf(a2.x, b2.x, acc[0][0]);
            acc[0][1] = fmaf(a2.x, b2.y, acc[0][1]);
            acc[1][0] = fmaf(a2.y, b2.x, acc[1][0]);
            acc[1][1] = fmaf(a2.y, b2.y, acc[1][1]);
        }
        __syncthreads();
    }
}

// N1: acc = K@K. A2 = cs^2*acc ; Bop = 2I + 2cs*K + 2cs^2*acc ; Zb0 = bf16(z0)
__global__ void __launch_bounds__(256)
n1_kernel(const float* __restrict__ K, const float* __restrict__ log_dt,
          const float* __restrict__ z0, float* __restrict__ A2,
          float* __restrict__ Bop, unsigned short* __restrict__ Zb0) {
    const float cs = 0.5f * expf(log_dt[0]);
    {
        int b = ((blockIdx.y * 8 + blockIdx.x) * 256 + threadIdx.x) * 4;
        uint2 w;
        w.x = pack2bf(z0[b], z0[b + 1]);
        w.y = pack2bf(z0[b + 2], z0[b + 3]);
        *(uint2*)(Zb0 + b) = w;
    }
    float acc[2][2];
    const int rowBase = blockIdx.y << 5, colBase = blockIdx.x << 5;
    g32_core(K, DD, K, DD, rowBase, colBase, acc);
    const float cs2 = cs * cs;
    const int r0 = rowBase + ((threadIdx.x >> 4) << 1);
    const int c0 = colBase + ((threadIdx.x & 15) << 1);
#pragma unroll
    for (int i = 0; i < 2; ++i) {
        int r = r0 + i;
        float e0 = K[(size_t)r * DD + c0], e1 = K[(size_t)r * DD + c0 + 1];
        float p0 = cs2 * acc[i][0], p1 = cs2 * acc[i][1];
        *(float2*)(A2 + (size_t)r * DD + c0) = (float2){p0, p1};
        float2 w;
        w.x = 2.f * p0 + 2.f * cs * e0 + (r == c0 ? 2.f : 0.f);
        w.y = 2.f * p1 + 2.f * cs * e1 + (r == c0 + 1 ? 2.f : 0.f);
        *(float2*)(Bop + (size_t)r * DD + c0) = w;
    }
}

// N2: E = Kd - I = A2@Bop + 2cs*K
__global__ void __launch_bounds__(256)
n2_kernel(const float* __restrict__ A2, const float* __restrict__ Bop,
          const float* __restrict__ K, const float* __restrict__ log_dt,
          float* __restrict__ E) {
    const float cs = 0.5f * expf(log_dt[0]);
    float acc[2][2];
    const int rowBase = blockIdx.y << 5, colBase = blockIdx.x << 5;
    g32_core(A2, DD, Bop, DD, rowBase, colBase, acc);
    const int r0 = rowBase + ((threadIdx.x >> 4) << 1);
    const int c0 = colBase + ((threadIdx.x & 15) << 1);
#pragma unroll
    for (int i = 0; i < 2; ++i) {
        int r = r0 + i;
        float e0 = K[(size_t)r * DD + c0], e1 = K[(size_t)r * DD + c0 + 1];
        float2 v;
        v.x = acc[i][0] + 2.f * cs * e0;
        v.y = acc[i][1] + 2.f * cs * e1;
        *(float2*)(E + (size_t)r * DD + c0) = v;
    }
}

// Generic batched 256^3 f32 GEMM for E-power stages 1-2.
__global__ void __launch_bounds__(256)
gpow_kernel(const float* __restrict__ A, const float* __restrict__ B,
            float* __restrict__ C, long long sA, long long sB, long long sC) {
    float acc[2][2];
    const int rowBase = blockIdx.y << 5, colBase = blockIdx.x << 5;
    g32_core(A + blockIdx.z * sA, DD, B + blockIdx.z * sB, DD, rowBase, colBase, acc);
    float* Cb = C + blockIdx.z * sC;
    const int r0 = rowBase + ((threadIdx.x >> 4) << 1);
    const int c0 = colBase + ((threadIdx.x & 15) << 1);
#pragma unroll
    for (int i = 0; i < 2; ++i) {
        int r = r0 + i;
        *(float2*)(Cb + (size_t)r * DD + c0) = (float2){acc[i][0], acc[i][1]};
    }
}

// E-power stage 3 (batch 4): E5=E2@E3, E6=E3@E3, E7=E3@E4, E8=E4@E4
__global__ void __launch_bounds__(256)
gpow4_kernel(float* __restrict__ Epow) {
    static const int sa[4] = {1, 2, 2, 3};
    static const int sb[4] = {2, 2, 3, 3};
    static const int sc[4] = {4, 5, 6, 7};
    const int z = blockIdx.z;
    float acc[2][2];
    const int rowBase = blockIdx.y << 5, colBase = blockIdx.x << 5;
    g32_core(Epow + (size_t)sa[z] * MATF, DD, Epow + (size_t)sb[z] * MATF, DD,
             rowBase, colBase, acc);
    float* Cb = Epow + (size_t)sc[z] * MATF;
    const int r0 = rowBase + ((threadIdx.x >> 4) << 1);
    const int c0 = colBase + ((threadIdx.x & 15) << 1);
#pragma unroll
    for (int i = 0; i < 2; ++i) {
        int r = r0 + i;
        *(float2*)(Cb + (size_t)r * DD + c0) = (float2){acc[i][0], acc[i][1]};
    }
}

// comb: M_j = (I+E)^j = I + sum_{m<=8} C(j,m)E^m, j=1..32 -> bf16 MTb[j][c][k],
// plus f32 W1=(I+E)^32, W2=(I+E)^64, W3=(I+E)^96.
__global__ void __launch_bounds__(256)
comb_kernel(const float* __restrict__ Epow, unsigned short* __restrict__ MTb,
            float* __restrict__ W1, float* __restrict__ W2,
            float* __restrict__ W3) {
    __shared__ float tle[8][32][33];
    const int tid = threadIdx.x;
    const int k0 = blockIdx.y << 5, c0 = blockIdx.x << 5;
    const int ltx = tid & 31, lty = tid >> 5;
#pragma unroll
    for (int m = 0; m < 8; ++m)
#pragma unroll
        for (int it = 0; it < 4; ++it) {
            int k = lty + (it << 3);
            tle[m][ltx][k] =
                Epow[(size_t)m * MATF + (size_t)(k0 + k) * DD + c0 + ltx];
        }
    __syncthreads();

    const int c = tid >> 3;
    const int kb = (tid & 7) << 2;
    float em[8][4];
#pragma unroll
    for (int m = 0; m < 8; ++m)
#pragma unroll
        for (int u = 0; u < 4; ++u) em[m][u] = tle[m][c][kb + u];

    float diag[4];
#pragma unroll
    for (int u = 0; u < 4; ++u)
        diag[u] = ((k0 + kb + u) == (c0 + c)) ? 1.f : 0.f;

    float w32[4];
    for (int j = 1; j <= 32; ++j) {
        float val[4] = {diag[0], diag[1], diag[2], diag[3]};
        long long coef = 1;
#pragma unroll
        for (int m = 1; m <= 8; ++m) {
            coef = coef * (j - m + 1) / m;
            float cf = (float)(coef < 0 ? 0 : coef);
#pragma unroll
            for (int u = 0; u < 4; ++u) val[u] = fmaf(cf, em[m - 1][u], val[u]);
        }
        uint2 w;
        w.x = pack2bf(val[0], val[1]);
        w.y = pack2bf(val[2], val[3]);
        *(uint2*)(MTb + (size_t)(j - 1) * MATF + (size_t)(c0 + c) * DD + k0 + kb) = w;
        if (j == 32) {
            w32[0] = val[0]; w32[1] = val[1]; w32[2] = val[2]; w32[3] = val[3];
        }
    }
    float w64[4] = {diag[0], diag[1], diag[2], diag[3]};
    float w96[4] = {diag[0], diag[1], diag[2], diag[3]};
    {
        double c64 = 1.0, c96 = 1.0;
#pragma unroll
        for (int m = 1; m <= 8; ++m) {
            c64 = c64 * (double)(64 - m + 1) / (double)m;
            c96 = c96 * (double)(96 - m + 1) / (double)m;
            float f64 = (float)c64, f96 = (float)c96;
#pragma unroll
            for (int u = 0; u < 4; ++u) {
                w64[u] = fmaf(f64, em[m - 1][u], w64[u]);
                w96[u] = fmaf(f96, em[m - 1][u], w96[u]);
            }
        }
    }
    float* tw = &tle[0][0][0];
    const int wk = tid >> 3, wc = (tid & 7) << 2;
    float* Wd[3] = {W1, W2, W3};
    float* Ws[3] = {w32, w64, w96};
#pragma unroll
    for (int p = 0; p < 3; ++p) {
        __syncthreads();
#pragma unroll
        for (int u = 0; u < 4; ++u) tw[(kb + u) * 33 + c] = Ws[p][u];
        __syncthreads();
        float4 v = {tw[wk * 33 + wc], tw[wk * 33 + wc + 1],
                    tw[wk * 33 + wc + 2], tw[wk * 33 + wc + 3]};
        *(float4*)(Wd[p] + (size_t)(k0 + wk) * DD + c0 + wc) = v;
    }
}

// 3-level checkpoint scan (proven r10).
__global__ void __launch_bounds__(256)
scan3_kernel(const float* __restrict__ z0, float* __restrict__ out,
             const float* __restrict__ W1, const float* __restrict__ W2,
             const float* __restrict__ W3, float* __restrict__ Wtab,
             unsigned short* __restrict__ Zb, int level) {
    static const signed char JA[3][7] = {{0, 0, 0, 17, 18, 0, 0},
                                         {0, 1, 2, 3, 2, 3, 20},
                                         {4, 5, 0, 1, 2, 3, 0}};
    static const signed char JB[3][7] = {{0, 1, 2, 1, 2, 0, 0},
                                         {3, 3, 3, 3, 4, 4, 4},
                                         {4, 4, 5, 5, 5, 5, 0}};
    static const signed char JD[3][7] = {{1, 2, 3, 19, 20, 0, 0},
                                         {4, 5, 6, 7, 8, 9, 21},
                                         {10, 11, 12, 13, 14, 15, 0}};
    const float* Wp[6] = {W1, W2, W3, Wtab, Wtab + MATF, Wtab + 2 * (size_t)MATF};
    const int jz = blockIdx.z;
    const int a = JA[level][jz], b = JB[level][jz], d = JD[level][jz];

    const float* Asrc;
    int lda;
    if (a == 0) { Asrc = z0; lda = DD; }
    else if (a < 16) { Asrc = out + (size_t)(32 * a - 1) * DD; lda = (int)LDT; }
    else { Asrc = Wp[a - 16]; lda = DD; }

    float acc[2][2];
    const int rowBase = blockIdx.y << 5, colBase = blockIdx.x << 5;
    g32_core(Asrc, lda, Wp[b], DD, rowBase, colBase, acc);

    const int r0 = rowBase + ((threadIdx.x >> 4) << 1);
    const int c0 = colBase + ((threadIdx.x & 15) << 1);
    if (d < 16) {
        float* Of = out + (size_t)(32 * d - 1) * DD;
        unsigned short* Zo = Zb + (size_t)d * MATF;
#pragma unroll
        for (int ii = 0; ii < 2; ++ii) {
            int r = r0 + ii;
            float2 v = {acc[ii][0], acc[ii][1]};
            *(float2*)(Of + (size_t)r * LDT + c0) = v;
            *(unsigned*)(Zo + (size_t)r * DD + c0) = pack2bf(v.x, v.y);
        }
    } else {
        float* Cb = Wtab + (size_t)(d - 19) * MATF;
#pragma unroll
        for (int ii = 0; ii < 2; ++ii) {
            int r = r0 + ii;
            *(float2*)(Cb + (size_t)r * DD + c0) = (float2){acc[ii][0], acc[ii][1]};
        }
    }
}

// r11 fill: ONE block per timestep (497 blocks, 512 threads, 8 waves).
// out[:, t, :] = Zb[i] @ M_j  (256x256x256, K_BLK=64, 4 rounds).
// Wave tile 128x64 (8x4 fragments). 64KB LDS single-buffer {A 32K | B 32K},
// reused for the 4-pass C epilogue (64 rows x 256 cols f32 per pass,
// full-1KB-row coalesced stores).
__global__ void __launch_bounds__(512, 2)
fill_kernel(const unsigned short* __restrict__ Zb,
            const unsigned short* __restrict__ MTb,
            float* __restrict__ out) {
    __shared__ __align__(16) char pool[65536];
    const int bz = blockIdx.x;
    const int i = (bz >= 465) ? 15 : bz / 31;
    const int j = bz - i * 31 + 1;
    const int t = i * 32 + j - 1;
    const unsigned short* Zt = Zb + (size_t)i * MATF;         // [row][k]
    const unsigned short* MT = MTb + (size_t)(j - 1) * MATF;  // [col][k]

    const int tid = threadIdx.x;
    const int lane = tid & 63, wid = tid >> 6;
    const int wr = (wid >> 2) * 128, wc = (wid & 3) * 64;

    // staging geometry: 2048 16B-chunks per matrix, 4 per thread
    int rowq[4], skq[4], ldsb[4];
#pragma unroll
    for (int q = 0; q < 4; ++q) {
        int c = q * 512 + wid * 64 + lane;
        int row = c >> 3;
        rowq[q] = row;
        skq[q] = ((c ^ row) & 7) << 3;        // pre-swizzled src k-offset (elems)
        ldsb[q] = (q * 512 + wid * 64) << 4;  // wave-uniform LDS byte base
    }

    f32x4 acc[8][4];
#pragma unroll
    for (int a = 0; a < 8; ++a)
#pragma unroll
        for (int b = 0; b < 4; ++b) acc[a][b] = (f32x4){0.f, 0.f, 0.f, 0.f};

    auto stage = [&](int k0) {
#pragma unroll
        for (int q = 0; q < 4; ++q) {
            GLD16(Zt + (size_t)rowq[q] * DD + k0 + skq[q], pool + ldsb[q]);
            GLD16(MT + (size_t)rowq[q] * DD + k0 + skq[q], pool + 32768 + ldsb[q]);
        }
    };

    for (int r = 0; r < 4; ++r) {
        stage(r * 64);
        __syncthreads();  // drain vmcnt -> staged data visible
        const char* asb = pool;
        const char* bsb = pool + 32768;
#pragma unroll
        for (int ks = 0; ks < 2; ++ks) {
            bf16x8 af[8], bg[4];
            const int kk = ks * 32 + (lane >> 4) * 8;
#pragma unroll
            for (int f = 0; f < 8; ++f) {
                int rr = wr + f * 16 + (lane & 15);
                af[f] = *(const bf16x8*)(asb + ((rr * 128 + kk * 2) ^ ((rr & 7) << 4)));
            }
#pragma unroll
            for (int f = 0; f < 4; ++f) {
                int cc = wc + f * 16 + (lane & 15);
                bg[f] = *(const bf16x8*)(bsb + ((cc * 128 + kk * 2) ^ ((cc & 7) << 4)));
            }
#pragma unroll
            for (int fr = 0; fr < 8; ++fr)
#pragma unroll
                for (int fc = 0; fc < 4; ++fc)
                    acc[fr][fc] = __builtin_amdgcn_mfma_f32_16x16x32_bf16(
                        af[fr], bg[fc], acc[fr][fc], 0, 0, 0);
        }
        __syncthreads();  // all waves done reading before next overwrite
    }

    // C epilogue: 4 passes of 64 rows x 256 cols f32 (64KB) through LDS.
    float* Cs = (float*)pool;
    float* C = out + (size_t)t * DD;
#pragma unroll
    for (int hp = 0; hp < 4; ++hp) {
        __syncthreads();
        if ((wid >> 2) == (hp >> 1)) {
            const int fbase = (hp & 1) * 4;
#pragma unroll
            for (int f = 0; f < 4; ++f) {
#pragma unroll
                for (int fc = 0; fc < 4; ++fc) {
                    int ccol = wc + fc * 16 + (lane & 15);
#pragma unroll
                    for (int ii = 0; ii < 4; ++ii) {
                        int lr = f * 16 + ((lane >> 4) << 2) + ii;  // 0..63
                        int csw = ccol ^ (((lr >> 2) & 3) << 4);
                        Cs[lr * 256 + csw] = acc[fbase + f][fc][ii];
                    }
                }
            }
        }
        __syncthreads();
#pragma unroll
        for (int it = 0; it < 8; ++it) {
            int chunk = it * 512 + tid;  // 0..4095
            int row = chunk >> 6;        // 0..63
            int c4 = (chunk & 63) << 2;
            int csw = c4 ^ (((row >> 2) & 3) << 4);
            float4 v = *(const float4*)(Cs + row * 256 + csw);
            *(float4*)(C + (size_t)(hp * 64 + row) * LDT + c4) = v;
        }
    }
}

// ---------------- fallback (tiny ws): proven g32 chain ----------------------
__global__ void prep_kernel(const float* __restrict__ K,
                            const float* __restrict__ log_dt,
                            float* __restrict__ A) {
    int idx = blockIdx.x * blockDim.x + threadIdx.x;
    A[idx] = 0.5f * expf(log_dt[0]) * K[idx];
}

template <int EPI>
__global__ void __launch_bounds__(256)
g32_kernel(const float* A, const float* B, float* C, const float* E, float* C2,
           int lda, int ldb, int ldc, long long sA, long long sB, long long sC) {
    float acc[2][2];
    const int rowBase = blockIdx.y << 5, colBase = blockIdx.x << 5;
    g32_core(A + blockIdx.z * sA, lda, B + blockIdx.z * sB, ldb, rowBase, colBase, acc);
    float* Cb = C + blockIdx.z * sC;
    const int r0 = rowBase + ((threadIdx.x >> 4) << 1);
    const int c0 = colBase + ((threadIdx.x & 15) << 1);
#pragma unroll
    for (int i = 0; i < 2; ++i) {
        int r = r0 + i;
        float2 v;
        if (EPI == 2) {
            float e0 = E[(size_t)r * DD + c0], e1 = E[(size_t)r * DD + c0 + 1];
            v.x = acc[i][0] + 2.f * e0 + (r == c0 ? 1.f : 0.f);
            v.y = acc[i][1] + 2.f * e1 + (r == c0 + 1 ? 1.f : 0.f);
        } else {
            v.x = acc[i][0];
            v.y = acc[i][1];
        }
        *(float2*)(Cb + (size_t)r * ldc + c0) = v;
        if (EPI == 1) {
            float e0 = E[(size_t)r * DD + c0], e1 = E[(size_t)r * DD + c0 + 1];
            float2 w;
            w.x = 2.f * acc[i][0] + 2.f * e0 + (r == c0 ? 2.f : 0.f);
            w.y = 2.f * acc[i][1] + 2.f * e1 + (r == c0 + 1 ? 2.f : 0.f);
            *(float2*)(C2 + (size_t)r * DD + c0) = w;
        }
    }
}

// ---------------- launch ----------------------------------------------------
extern "C" void kernel_launch(void* const* d_in, const int* in_sizes, int n_in,
                              void* d_out, int out_size, void* d_ws, size_t ws_size,
                              hipStream_t stream) {
    const float* z0 = (const float*)d_in[0];
    const float* Kmat = (const float*)d_in[1];
    const float* log_dt = (const float*)d_in[2];
    float* out = (float*)d_out;

    dim3 blk(256);

    // ws: A2 | Bop | Epow[8] | W1 | W2 | W3 | Wtab[3] f32 | MTb[32] | Zb[16] bf16
    float* A2 = (float*)d_ws;
    float* Bop = A2 + MATF;
    float* Epow = Bop + MATF;
    float* W1 = Epow + (size_t)8 * MATF;
    float* W2 = W1 + MATF;
    float* W3 = W2 + MATF;
    float* Wtab = W3 + MATF;
    unsigned short* MTb = (unsigned short*)(Wtab + (size_t)3 * MATF);
    unsigned short* Zb = MTb + (size_t)32 * MATF;
    const size_t need = (size_t)16 * MATF * 4 + (size_t)48 * MATF * 2;

    if (ws_size >= need) {
        dim3 g(8, 8, 1);
        // Neumann order-4 -> E = Kd - I (2 launches)
        n1_kernel<<<g, blk, 0, stream>>>(Kmat, log_dt, z0, A2, Bop, Zb);
        n2_kernel<<<g, blk, 0, stream>>>(A2, Bop, Kmat, log_dt, Epow);

        // E-powers: E2 ; {E3,E4} ; {E5,E6,E7,E8}
        gpow_kernel<<<g, blk, 0, stream>>>(Epow, Epow, Epow + MATF, 0, 0, 0);
        gpow_kernel<<<dim3(8, 8, 2), blk, 0, stream>>>(
            Epow, Epow + MATF, Epow + 2 * (size_t)MATF, MATF, 0, MATF);
        gpow4_kernel<<<dim3(8, 8, 4), blk, 0, stream>>>(Epow);

        // All 32 M-tables (bf16-T) + W1/W2/W3 f32, one launch
        comb_kernel<<<g, blk, 0, stream>>>(Epow, MTb, W1, W2, W3);

        // checkpoint scan: 3 batched levels
        const int njobs[3] = {5, 7, 6};
        for (int s = 0; s < 3; ++s)
            scan3_kernel<<<dim3(8, 8, njobs[s]), blk, 0, stream>>>(
                z0, out, W1, W2, W3, Wtab, Zb, s);

        // All 497 remaining timesteps: one block per timestep
        fill_kernel<<<dim3(497), dim3(512), 0, stream>>>(Zb, MTb, out);
        return;
    }

    // Minimal fallback (tiny ws): Kd then 512 chained GEMMs (f32, proven core).
    float* A = (float*)d_ws;
    float* A2f = A + MATF;
    float* Bopf = A2f + MATF;
    float* Kd = Bopf + MATF;
    prep_kernel<<<MATF / 256, blk, 0, stream>>>(Kmat, log_dt, A);
    dim3 g(8, 8, 1);
    g32_kernel<1><<<g, blk, 0, stream>>>(A, A, A2f, A, Bopf, DD, DD, DD, 0, 0, 0);
    g32_kernel<2><<<g, blk, 0, stream>>>(A2f, Bopf, Kd, A, (float*)0, DD, DD, DD, 0, 0, 0);
    for (int t = 0; t < TT; ++t) {
        const float* Ain = (t == 0) ? z0 : out + (size_t)(t - 1) * DD;
        int lda = (t == 0) ? DD : (int)LDT;
        g32_kernel<0><<<g, blk, 0, stream>>>(Ain, Kd, out + (size_t)t * DD,
                                             (const float*)0, (float*)0,
                                             lda, DD, (int)LDT, 0, 0, 0);
    }
}

// Round 12
// 116.112 us; speedup vs baseline: 1.0753x; 1.0753x over previous
//
#include <hip/hip_runtime.h>

// Koopman bilinear rollout: preds[b,t,d] = (z0 @ Kd^{t+1})[b,d], D=B=256, T=512.
// Kd = (I-A)^-1(I+A), A=0.5*dt*K -> order-4 Neumann (2 launches, proven r2-r11).
// E-powers E^2..E^8 in 3 GEMM stages; comb writes all 32 bf16-T M-tables and
// W1/W2/W3=(I+E)^{32,64,96} f32; 3-level checkpoint scan kept f32 in a
// CONTIGUOUS ws buffer Zf (r12: no more 512KB-stride reads/writes on the
// chain critical path); ONE batched bf16-MFMA fill covers ALL 512 timesteps
// (t = blockIdx.z; checkpoint rows are bf16 products like their neighbors).
// DEAD ENDS (do not retry): persistent kernel + grid barrier (r5 392us,
// r7 289us -- cache-maintenance storm); 256x256 fill tile (r11, -5us).
// r10 lesson: marginal launch ~0.5-2us; bulk stage removal is what pays.

#define DD 256
#define TT 512
#define MATF (DD * DD)
#define LDT ((size_t)TT * (size_t)DD)

typedef __attribute__((ext_vector_type(8))) short bf16x8;
typedef __attribute__((ext_vector_type(4))) float f32x4;

#define GLD16(g, l)                                                  \
    __builtin_amdgcn_global_load_lds(                                \
        (const __attribute__((address_space(1))) void*)(g),          \
        (__attribute__((address_space(3))) void*)(l), 16, 0, 0)

static __device__ __forceinline__ unsigned short f2bf(float f) {
    unsigned int u = __float_as_uint(f);
    u += 0x7fffu + ((u >> 16) & 1u);
    return (unsigned short)(u >> 16);
}
static __device__ __forceinline__ unsigned pack2bf(float a, float b) {
    return (unsigned)f2bf(a) | ((unsigned)f2bf(b) << 16);
}

// ---- 32x32-tile f32 GEMM core: 256 threads, K=256, K_BLK=64, reg prefetch ----
__device__ __forceinline__ void g32_core(const float* __restrict__ Ab, int lda,
                                         const float* __restrict__ Bb, int ldb,
                                         int rowBase, int colBase, float acc[2][2]) {
    __shared__ __align__(16) float As[64 * 38];
    __shared__ __align__(16) float Bs[64 * 40];
    const int tid = threadIdx.x;
    const int tx = tid & 15, ty = tid >> 4;
    const int am = tid >> 4;
    const int ak = (tid & 15) << 2;
    const int bk = tid >> 3;
    const int bn = (tid & 7) << 2;

    acc[0][0] = acc[0][1] = acc[1][0] = acc[1][1] = 0.f;

    float4 pa0 = *(const float4*)(Ab + (size_t)(rowBase + am) * lda + ak);
    float4 pa1 = *(const float4*)(Ab + (size_t)(rowBase + am + 16) * lda + ak);
    float4 pb0 = *(const float4*)(Bb + (size_t)bk * ldb + colBase + bn);
    float4 pb1 = *(const float4*)(Bb + (size_t)(bk + 32) * ldb + colBase + bn);

    for (int k0 = 0; k0 < DD; k0 += 64) {
        As[(ak + 0) * 38 + am] = pa0.x;
        As[(ak + 1) * 38 + am] = pa0.y;
        As[(ak + 2) * 38 + am] = pa0.z;
        As[(ak + 3) * 38 + am] = pa0.w;
        As[(ak + 0) * 38 + am + 16] = pa1.x;
        As[(ak + 1) * 38 + am + 16] = pa1.y;
        As[(ak + 2) * 38 + am + 16] = pa1.z;
        As[(ak + 3) * 38 + am + 16] = pa1.w;
        *(float4*)(&Bs[bk * 40 + bn]) = pb0;
        *(float4*)(&Bs[(bk + 32) * 40 + bn]) = pb1;
        __syncthreads();
        if (k0 + 64 < DD) {
            pa0 = *(const float4*)(Ab + (size_t)(rowBase + am) * lda + k0 + 64 + ak);
            pa1 = *(const float4*)(Ab + (size_t)(rowBase + am + 16) * lda + k0 + 64 + ak);
            pb0 = *(const float4*)(Bb + (size_t)(bk + k0 + 64) * ldb + colBase + bn);
            pb1 = *(const float4*)(Bb + (size_t)(bk + 32 + k0 + 64) * ldb + colBase + bn);
        }
#pragma unroll
        for (int kk = 0; kk < 64; ++kk) {
            float2 a2 = *(const float2*)(&As[kk * 38 + (ty << 1)]);
            float2 b2 = *(const float2*)(&Bs[kk * 40 + (tx << 1)]);
            acc[0][0] = fmaf(a2.x, b2.x, acc[0][0]);
            acc[0][1] = fmaf(a2.x, b2.y, acc[0][1]);
            acc[1][0] = fmaf(a2.y, b2.x, acc[1][0]);
            acc[1][1] = fmaf(a2.y, b2.y, acc[1][1]);
        }
        __syncthreads();
    }
}

// N1: acc = K@K. A2 = cs^2*acc ; Bop = 2I + 2cs*K + 2cs^2*acc ; Zb0 = bf16(z0)
__global__ void __launch_bounds__(256)
n1_kernel(const float* __restrict__ K, const float* __restrict__ log_dt,
          const float* __restrict__ z0, float* __restrict__ A2,
          float* __restrict__ Bop, unsigned short* __restrict__ Zb0) {
    const float cs = 0.5f * expf(log_dt[0]);
    {
        int b = ((blockIdx.y * 8 + blockIdx.x) * 256 + threadIdx.x) * 4;
        uint2 w;
        w.x = pack2bf(z0[b], z0[b + 1]);
        w.y = pack2bf(z0[b + 2], z0[b + 3]);
        *(uint2*)(Zb0 + b) = w;
    }
    float acc[2][2];
    const int rowBase = blockIdx.y << 5, colBase = blockIdx.x << 5;
    g32_core(K, DD, K, DD, rowBase, colBase, acc);
    const float cs2 = cs * cs;
    const int r0 = rowBase + ((threadIdx.x >> 4) << 1);
    const int c0 = colBase + ((threadIdx.x & 15) << 1);
#pragma unroll
    for (int i = 0; i < 2; ++i) {
        int r = r0 + i;
        float e0 = K[(size_t)r * DD + c0], e1 = K[(size_t)r * DD + c0 + 1];
        float p0 = cs2 * acc[i][0], p1 = cs2 * acc[i][1];
        *(float2*)(A2 + (size_t)r * DD + c0) = (float2){p0, p1};
        float2 w;
        w.x = 2.f * p0 + 2.f * cs * e0 + (r == c0 ? 2.f : 0.f);
        w.y = 2.f * p1 + 2.f * cs * e1 + (r == c0 + 1 ? 2.f : 0.f);
        *(float2*)(Bop + (size_t)r * DD + c0) = w;
    }
}

// N2: E = Kd - I = A2@Bop + 2cs*K
__global__ void __launch_bounds__(256)
n2_kernel(const float* __restrict__ A2, const float* __restrict__ Bop,
          const float* __restrict__ K, const float* __restrict__ log_dt,
          float* __restrict__ E) {
    const float cs = 0.5f * expf(log_dt[0]);
    float acc[2][2];
    const int rowBase = blockIdx.y << 5, colBase = blockIdx.x << 5;
    g32_core(A2, DD, Bop, DD, rowBase, colBase, acc);
    const int r0 = rowBase + ((threadIdx.x >> 4) << 1);
    const int c0 = colBase + ((threadIdx.x & 15) << 1);
#pragma unroll
    for (int i = 0; i < 2; ++i) {
        int r = r0 + i;
        float e0 = K[(size_t)r * DD + c0], e1 = K[(size_t)r * DD + c0 + 1];
        float2 v;
        v.x = acc[i][0] + 2.f * cs * e0;
        v.y = acc[i][1] + 2.f * cs * e1;
        *(float2*)(E + (size_t)r * DD + c0) = v;
    }
}

// Generic batched 256^3 f32 GEMM for E-power stages 1-2.
__global__ void __launch_bounds__(256)
gpow_kernel(const float* __restrict__ A, const float* __restrict__ B,
            float* __restrict__ C, long long sA, long long sB, long long sC) {
    float acc[2][2];
    const int rowBase = blockIdx.y << 5, colBase = blockIdx.x << 5;
    g32_core(A + blockIdx.z * sA, DD, B + blockIdx.z * sB, DD, rowBase, colBase, acc);
    float* Cb = C + blockIdx.z * sC;
    const int r0 = rowBase + ((threadIdx.x >> 4) << 1);
    const int c0 = colBase + ((threadIdx.x & 15) << 1);
#pragma unroll
    for (int i = 0; i < 2; ++i) {
        int r = r0 + i;
        *(float2*)(Cb + (size_t)r * DD + c0) = (float2){acc[i][0], acc[i][1]};
    }
}

// E-power stage 3 (batch 4): E5=E2@E3, E6=E3@E3, E7=E3@E4, E8=E4@E4
__global__ void __launch_bounds__(256)
gpow4_kernel(float* __restrict__ Epow) {
    static const int sa[4] = {1, 2, 2, 3};
    static const int sb[4] = {2, 2, 3, 3};
    static const int sc[4] = {4, 5, 6, 7};
    const int z = blockIdx.z;
    float acc[2][2];
    const int rowBase = blockIdx.y << 5, colBase = blockIdx.x << 5;
    g32_core(Epow + (size_t)sa[z] * MATF, DD, Epow + (size_t)sb[z] * MATF, DD,
             rowBase, colBase, acc);
    float* Cb = Epow + (size_t)sc[z] * MATF;
    const int r0 = rowBase + ((threadIdx.x >> 4) << 1);
    const int c0 = colBase + ((threadIdx.x & 15) << 1);
#pragma unroll
    for (int i = 0; i < 2; ++i) {
        int r = r0 + i;
        *(float2*)(Cb + (size_t)r * DD + c0) = (float2){acc[i][0], acc[i][1]};
    }
}

// comb: M_j = (I+E)^j = I + sum_{m<=8} C(j,m)E^m, j=1..32 -> bf16 MTb[j][c][k],
// plus f32 W1=(I+E)^32, W2=(I+E)^64, W3=(I+E)^96.
__global__ void __launch_bounds__(256)
comb_kernel(const float* __restrict__ Epow, unsigned short* __restrict__ MTb,
            float* __restrict__ W1, float* __restrict__ W2,
            float* __restrict__ W3) {
    __shared__ float tle[8][32][33];
    const int tid = threadIdx.x;
    const int k0 = blockIdx.y << 5, c0 = blockIdx.x << 5;
    const int ltx = tid & 31, lty = tid >> 5;
#pragma unroll
    for (int m = 0; m < 8; ++m)
#pragma unroll
        for (int it = 0; it < 4; ++it) {
            int k = lty + (it << 3);
            tle[m][ltx][k] =
                Epow[(size_t)m * MATF + (size_t)(k0 + k) * DD + c0 + ltx];
        }
    __syncthreads();

    const int c = tid >> 3;
    const int kb = (tid & 7) << 2;
    float em[8][4];
#pragma unroll
    for (int m = 0; m < 8; ++m)
#pragma unroll
        for (int u = 0; u < 4; ++u) em[m][u] = tle[m][c][kb + u];

    float diag[4];
#pragma unroll
    for (int u = 0; u < 4; ++u)
        diag[u] = ((k0 + kb + u) == (c0 + c)) ? 1.f : 0.f;

    float w32[4];
    for (int j = 1; j <= 32; ++j) {
        float val[4] = {diag[0], diag[1], diag[2], diag[3]};
        long long coef = 1;
#pragma unroll
        for (int m = 1; m <= 8; ++m) {
            coef = coef * (j - m + 1) / m;
            float cf = (float)(coef < 0 ? 0 : coef);
#pragma unroll
            for (int u = 0; u < 4; ++u) val[u] = fmaf(cf, em[m - 1][u], val[u]);
        }
        uint2 w;
        w.x = pack2bf(val[0], val[1]);
        w.y = pack2bf(val[2], val[3]);
        *(uint2*)(MTb + (size_t)(j - 1) * MATF + (size_t)(c0 + c) * DD + k0 + kb) = w;
        if (j == 32) {
            w32[0] = val[0]; w32[1] = val[1]; w32[2] = val[2]; w32[3] = val[3];
        }
    }
    float w64[4] = {diag[0], diag[1], diag[2], diag[3]};
    float w96[4] = {diag[0], diag[1], diag[2], diag[3]};
    {
        double c64 = 1.0, c96 = 1.0;
#pragma unroll
        for (int m = 1; m <= 8; ++m) {
            c64 = c64 * (double)(64 - m + 1) / (double)m;
            c96 = c96 * (double)(96 - m + 1) / (double)m;
            float f64 = (float)c64, f96 = (float)c96;
#pragma unroll
            for (int u = 0; u < 4; ++u) {
                w64[u] = fmaf(f64, em[m - 1][u], w64[u]);
                w96[u] = fmaf(f96, em[m - 1][u], w96[u]);
            }
        }
    }
    float* tw = &tle[0][0][0];
    const int wk = tid >> 3, wc = (tid & 7) << 2;
    float* Wd[3] = {W1, W2, W3};
    float* Ws[3] = {w32, w64, w96};
#pragma unroll
    for (int p = 0; p < 3; ++p) {
        __syncthreads();
#pragma unroll
        for (int u = 0; u < 4; ++u) tw[(kb + u) * 33 + c] = Ws[p][u];
        __syncthreads();
        float4 v = {tw[wk * 33 + wc], tw[wk * 33 + wc + 1],
                    tw[wk * 33 + wc + 2], tw[wk * 33 + wc + 3]};
        *(float4*)(Wd[p] + (size_t)(k0 + wk) * DD + c0 + wc) = v;
    }
}

// 3-level checkpoint scan, all operands CONTIGUOUS (r12).
// Z_d (f32) lives in Zf[d] (dense 256x256); bf16 copy in Zb[d] for fill.
// a: 0=z0, 1..15=Zf[a], 16+k=Wp[k]; b: Wp index; d: 1..15=Z_dst, 19/20/21=Wtab.
// Wp = {W1, W2, W3, Wtab+0 (W4), Wtab+1 (W6), Wtab+2 (W12)}.
__global__ void __launch_bounds__(256)
scan3_kernel(const float* __restrict__ z0, float* __restrict__ Zf,
             const float* __restrict__ W1, const float* __restrict__ W2,
             const float* __restrict__ W3, float* __restrict__ Wtab,
             unsigned short* __restrict__ Zb, int level) {
    static const signed char JA[3][7] = {{0, 0, 0, 17, 18, 0, 0},
                                         {0, 1, 2, 3, 2, 3, 20},
                                         {4, 5, 0, 1, 2, 3, 0}};
    static const signed char JB[3][7] = {{0, 1, 2, 1, 2, 0, 0},
                                         {3, 3, 3, 3, 4, 4, 4},
                                         {4, 4, 5, 5, 5, 5, 0}};
    static const signed char JD[3][7] = {{1, 2, 3, 19, 20, 0, 0},
                                         {4, 5, 6, 7, 8, 9, 21},
                                         {10, 11, 12, 13, 14, 15, 0}};
    const float* Wp[6] = {W1, W2, W3, Wtab, Wtab + MATF, Wtab + 2 * (size_t)MATF};
    const int jz = blockIdx.z;
    const int a = JA[level][jz], b = JB[level][jz], d = JD[level][jz];

    const float* Asrc;
    if (a == 0) Asrc = z0;
    else if (a < 16) Asrc = Zf + (size_t)a * MATF;
    else Asrc = Wp[a - 16];

    float acc[2][2];
    const int rowBase = blockIdx.y << 5, colBase = blockIdx.x << 5;
    g32_core(Asrc, DD, Wp[b], DD, rowBase, colBase, acc);

    const int r0 = rowBase + ((threadIdx.x >> 4) << 1);
    const int c0 = colBase + ((threadIdx.x & 15) << 1);
    if (d < 16) {
        float* Zo32 = Zf + (size_t)d * MATF;
        unsigned short* Zo = Zb + (size_t)d * MATF;
#pragma unroll
        for (int ii = 0; ii < 2; ++ii) {
            int r = r0 + ii;
            float2 v = {acc[ii][0], acc[ii][1]};
            *(float2*)(Zo32 + (size_t)r * DD + c0) = v;
            *(unsigned*)(Zo + (size_t)r * DD + c0) = pack2bf(v.x, v.y);
        }
    } else {
        float* Cb = Wtab + (size_t)(d - 19) * MATF;
#pragma unroll
        for (int ii = 0; ii < 2; ++ii) {
            int r = r0 + ii;
            *(float2*)(Cb + (size_t)r * DD + c0) = (float2){acc[ii][0], acc[ii][1]};
        }
    }
}

// Batched bf16 MFMA fill (proven r8/r10 core), now covering ALL 512 timesteps:
// t = blockIdx.z; i = t>>5; j = (t&31)+1; out[:, t, :] = Zb[i] @ M_j.
// 128x128 tile, 4 waves, single-buffered 32KB LDS, two-pass LDS-staged C write.
__global__ void __launch_bounds__(256)
fill_kernel(const unsigned short* __restrict__ Zb,
            const unsigned short* __restrict__ MTb,
            float* __restrict__ out) {
    __shared__ __align__(16) char pool[32768];
    const int t = blockIdx.z;
    const int i = t >> 5;
    const int j = (t & 31) + 1;
    const unsigned short* Zt = Zb + (size_t)i * MATF;
    const unsigned short* MT = MTb + (size_t)(j - 1) * MATF;

    const int tid = threadIdx.x;
    const int lane = tid & 63, wid = tid >> 6;
    const int rowBase = blockIdx.y * 128, colBase = blockIdx.x * 128;
    const int wr = (wid >> 1) * 64, wc = (wid & 1) * 64;

    int rowq[4], skq[4], ldsb[4];
#pragma unroll
    for (int q = 0; q < 4; ++q) {
        int c = q * 256 + wid * 64 + lane;
        int row = c >> 3;
        rowq[q] = row;
        skq[q] = ((c ^ (row & 7)) & 7) << 3;
        ldsb[q] = (q * 256 + wid * 64) << 4;
    }

    f32x4 acc[4][4];
#pragma unroll
    for (int a = 0; a < 4; ++a)
#pragma unroll
        for (int b = 0; b < 4; ++b) acc[a][b] = (f32x4){0.f, 0.f, 0.f, 0.f};

    auto stage = [&](int k0) {
#pragma unroll
        for (int q = 0; q < 4; ++q) {
            GLD16(Zt + (size_t)(rowBase + rowq[q]) * DD + k0 + skq[q], pool + ldsb[q]);
            GLD16(MT + (size_t)(colBase + rowq[q]) * DD + k0 + skq[q],
                  pool + 16384 + ldsb[q]);
        }
    };

    stage(0);
    for (int r = 0; r < 4; ++r) {
        __syncthreads();
        const char* asb = pool;
        const char* bsb = pool + 16384;
#pragma unroll
        for (int ks = 0; ks < 2; ++ks) {
            bf16x8 af[4], bg[4];
            const int kk = ks * 32 + (lane >> 4) * 8;
#pragma unroll
            for (int f = 0; f < 4; ++f) {
                int rr = wr + f * 16 + (lane & 15);
                af[f] = *(const bf16x8*)(asb + ((rr * 128 + kk * 2) ^ ((rr & 7) << 4)));
                int cc = wc + f * 16 + (lane & 15);
                bg[f] = *(const bf16x8*)(bsb + ((cc * 128 + kk * 2) ^ ((cc & 7) << 4)));
            }
#pragma unroll
            for (int fr = 0; fr < 4; ++fr)
#pragma unroll
                for (int fc = 0; fc < 4; ++fc)
                    acc[fr][fc] = __builtin_amdgcn_mfma_f32_16x16x32_bf16(
                        af[fr], bg[fc], acc[fr][fc], 0, 0, 0);
        }
        __syncthreads();
        if (r < 3) stage((r + 1) * 64);
    }

    float* Cs = (float*)pool;
    float* C = out + (size_t)t * DD;
#pragma unroll
    for (int hp = 0; hp < 2; ++hp) {
        __syncthreads();
        if (wr == hp * 64) {
#pragma unroll
            for (int fr = 0; fr < 4; ++fr) {
#pragma unroll
                for (int fc = 0; fc < 4; ++fc) {
                    int ccol = wc + fc * 16 + (lane & 15);
#pragma unroll
                    for (int ii = 0; ii < 4; ++ii) {
                        int lr = fr * 16 + ((lane >> 4) << 2) + ii;
                        int csw = ccol ^ (((lr >> 2) & 1) << 4);
                        Cs[lr * 128 + csw] = acc[fr][fc][ii];
                    }
                }
            }
        }
        __syncthreads();
#pragma unroll
        for (int it = 0; it < 8; ++it) {
            int chunk = it * 256 + tid;
            int row = chunk >> 5;
            int c4 = (chunk & 31) << 2;
            int csw = c4 ^ (((row >> 2) & 1) << 4);
            float4 v = *(const float4*)(Cs + row * 128 + csw);
            *(float4*)(C + (size_t)(rowBase + hp * 64 + row) * LDT + colBase + c4) = v;
        }
    }
}

// ---------------- fallback (tiny ws): proven g32 chain ----------------------
__global__ void prep_kernel(const float* __restrict__ K,
                            const float* __restrict__ log_dt,
                            float* __restrict__ A) {
    int idx = blockIdx.x * blockDim.x + threadIdx.x;
    A[idx] = 0.5f * expf(log_dt[0]) * K[idx];
}

template <int EPI>
__global__ void __launch_bounds__(256)
g32_kernel(const float* A, const float* B, float* C, const float* E, float* C2,
           int lda, int ldb, int ldc, long long sA, long long sB, long long sC) {
    float acc[2][2];
    const int rowBase = blockIdx.y << 5, colBase = blockIdx.x << 5;
    g32_core(A + blockIdx.z * sA, lda, B + blockIdx.z * sB, ldb, rowBase, colBase, acc);
    float* Cb = C + blockIdx.z * sC;
    const int r0 = rowBase + ((threadIdx.x >> 4) << 1);
    const int c0 = colBase + ((threadIdx.x & 15) << 1);
#pragma unroll
    for (int i = 0; i < 2; ++i) {
        int r = r0 + i;
        float2 v;
        if (EPI == 2) {
            float e0 = E[(size_t)r * DD + c0], e1 = E[(size_t)r * DD + c0 + 1];
            v.x = acc[i][0] + 2.f * e0 + (r == c0 ? 1.f : 0.f);
            v.y = acc[i][1] + 2.f * e1 + (r == c0 + 1 ? 1.f : 0.f);
        } else {
            v.x = acc[i][0];
            v.y = acc[i][1];
        }
        *(float2*)(Cb + (size_t)r * ldc + c0) = v;
        if (EPI == 1) {
            float e0 = E[(size_t)r * DD + c0], e1 = E[(size_t)r * DD + c0 + 1];
            float2 w;
            w.x = 2.f * acc[i][0] + 2.f * e0 + (r == c0 ? 2.f : 0.f);
            w.y = 2.f * acc[i][1] + 2.f * e1 + (r == c0 + 1 ? 2.f : 0.f);
            *(float2*)(C2 + (size_t)r * DD + c0) = w;
        }
    }
}

// ---------------- launch ----------------------------------------------------
extern "C" void kernel_launch(void* const* d_in, const int* in_sizes, int n_in,
                              void* d_out, int out_size, void* d_ws, size_t ws_size,
                              hipStream_t stream) {
    const float* z0 = (const float*)d_in[0];
    const float* Kmat = (const float*)d_in[1];
    const float* log_dt = (const float*)d_in[2];
    float* out = (float*)d_out;

    dim3 blk(256);

    // ws: A2 | Bop | Epow[8] | W1 | W2 | W3 | Wtab[3] | Zf[16] f32
    //     | MTb[32] | Zb[16] bf16
    float* A2 = (float*)d_ws;
    float* Bop = A2 + MATF;
    float* Epow = Bop + MATF;
    float* W1 = Epow + (size_t)8 * MATF;
    float* W2 = W1 + MATF;
    float* W3 = W2 + MATF;
    float* Wtab = W3 + MATF;
    float* Zf = Wtab + (size_t)3 * MATF;
    unsigned short* MTb = (unsigned short*)(Zf + (size_t)16 * MATF);
    unsigned short* Zb = MTb + (size_t)32 * MATF;
    const size_t need = (size_t)32 * MATF * 4 + (size_t)48 * MATF * 2;

    if (ws_size >= need) {
        dim3 g(8, 8, 1);
        // Neumann order-4 -> E = Kd - I (2 launches)
        n1_kernel<<<g, blk, 0, stream>>>(Kmat, log_dt, z0, A2, Bop, Zb);
        n2_kernel<<<g, blk, 0, stream>>>(A2, Bop, Kmat, log_dt, Epow);

        // E-powers: E2 ; {E3,E4} ; {E5,E6,E7,E8}
        gpow_kernel<<<g, blk, 0, stream>>>(Epow, Epow, Epow + MATF, 0, 0, 0);
        gpow_kernel<<<dim3(8, 8, 2), blk, 0, stream>>>(
            Epow, Epow + MATF, Epow + 2 * (size_t)MATF, MATF, 0, MATF);
        gpow4_kernel<<<dim3(8, 8, 4), blk, 0, stream>>>(Epow);

        // All 32 M-tables (bf16-T) + W1/W2/W3 f32, one launch
        comb_kernel<<<g, blk, 0, stream>>>(Epow, MTb, W1, W2, W3);

        // checkpoint scan: 3 batched levels, contiguous operands
        const int njobs[3] = {5, 7, 6};
        for (int s = 0; s < 3; ++s)
            scan3_kernel<<<dim3(8, 8, njobs[s]), blk, 0, stream>>>(
                z0, Zf, W1, W2, W3, Wtab, Zb, s);

        // ALL 512 timesteps in one batched MFMA launch (t = blockIdx.z)
        fill_kernel<<<dim3(2, 2, 512), blk, 0, stream>>>(Zb, MTb, out);
        return;
    }

    // Minimal fallback (tiny ws): Kd then 512 chained GEMMs (f32, proven core).
    float* A = (float*)d_ws;
    float* A2f = A + MATF;
    float* Bopf = A2f + MATF;
    float* Kd = Bopf + MATF;
    prep_kernel<<<MATF / 256, blk, 0, stream>>>(Kmat, log_dt, A);
    dim3 g(8, 8, 1);
    g32_kernel<1><<<g, blk, 0, stream>>>(A, A, A2f, A, Bopf, DD, DD, DD, 0, 0, 0);
    g32_kernel<2><<<g, blk, 0, stream>>>(A2f, Bopf, Kd, A, (float*)0, DD, DD, DD, 0, 0, 0);
    for (int t = 0; t < TT; ++t) {
        const float* Ain = (t == 0) ? z0 : out + (size_t)(t - 1) * DD;
        int lda = (t == 0) ? DD : (int)LDT;
        g32_kernel<0><<<g, blk, 0, stream>>>(Ain, Kd, out + (size_t)t * DD,
                                             (const float*)0, (float*)0,
                                             lda, DD, (int)LDT, 0, 0, 0);
    }
}

// Round 13
// 115.036 us; speedup vs baseline: 1.0854x; 1.0094x over previous
//
#include <hip/hip_runtime.h>

// Koopman bilinear rollout: preds[b,t,d] = (z0 @ Kd^{t+1})[b,d], D=B=256, T=512.
// Kd = (I-A)^-1(I+A), A=0.5*dt*K -> order-4 Neumann (2 launches, proven r2-r12).
// E-powers E^2..E^8 in 3 GEMM stages; comb writes all 32 bf16-T M-tables and
// W1/W2/W3=(I+E)^{32,64,96} f32; 3-level checkpoint scan in contiguous Zf;
// ONE batched bf16-MFMA fill covers ALL 512 timesteps.
// r13: fill job order j-MAJOR (zz=(j-1)*16+i) so the in-flight block window
// shares ~16 MTb tables (~3MB, L2-resident) instead of all 32 (+misses).
// DEAD ENDS (do not retry): persistent kernel + grid barrier (r5 392us,
// r7 289us -- cache-maintenance storm); 256x256 fill tile (r11, -5us).
// r10 lesson: marginal launch ~0.5-2us; bulk stage removal is what pays.

#define DD 256
#define TT 512
#define MATF (DD * DD)
#define LDT ((size_t)TT * (size_t)DD)

typedef __attribute__((ext_vector_type(8))) short bf16x8;
typedef __attribute__((ext_vector_type(4))) float f32x4;

#define GLD16(g, l)                                                  \
    __builtin_amdgcn_global_load_lds(                                \
        (const __attribute__((address_space(1))) void*)(g),          \
        (__attribute__((address_space(3))) void*)(l), 16, 0, 0)

static __device__ __forceinline__ unsigned short f2bf(float f) {
    unsigned int u = __float_as_uint(f);
    u += 0x7fffu + ((u >> 16) & 1u);
    return (unsigned short)(u >> 16);
}
static __device__ __forceinline__ unsigned pack2bf(float a, float b) {
    return (unsigned)f2bf(a) | ((unsigned)f2bf(b) << 16);
}

// ---- 32x32-tile f32 GEMM core: 256 threads, K=256, K_BLK=64, reg prefetch ----
__device__ __forceinline__ void g32_core(const float* __restrict__ Ab, int lda,
                                         const float* __restrict__ Bb, int ldb,
                                         int rowBase, int colBase, float acc[2][2]) {
    __shared__ __align__(16) float As[64 * 38];
    __shared__ __align__(16) float Bs[64 * 40];
    const int tid = threadIdx.x;
    const int tx = tid & 15, ty = tid >> 4;
    const int am = tid >> 4;
    const int ak = (tid & 15) << 2;
    const int bk = tid >> 3;
    const int bn = (tid & 7) << 2;

    acc[0][0] = acc[0][1] = acc[1][0] = acc[1][1] = 0.f;

    float4 pa0 = *(const float4*)(Ab + (size_t)(rowBase + am) * lda + ak);
    float4 pa1 = *(const float4*)(Ab + (size_t)(rowBase + am + 16) * lda + ak);
    float4 pb0 = *(const float4*)(Bb + (size_t)bk * ldb + colBase + bn);
    float4 pb1 = *(const float4*)(Bb + (size_t)(bk + 32) * ldb + colBase + bn);

    for (int k0 = 0; k0 < DD; k0 += 64) {
        As[(ak + 0) * 38 + am] = pa0.x;
        As[(ak + 1) * 38 + am] = pa0.y;
        As[(ak + 2) * 38 + am] = pa0.z;
        As[(ak + 3) * 38 + am] = pa0.w;
        As[(ak + 0) * 38 + am + 16] = pa1.x;
        As[(ak + 1) * 38 + am + 16] = pa1.y;
        As[(ak + 2) * 38 + am + 16] = pa1.z;
        As[(ak + 3) * 38 + am + 16] = pa1.w;
        *(float4*)(&Bs[bk * 40 + bn]) = pb0;
        *(float4*)(&Bs[(bk + 32) * 40 + bn]) = pb1;
        __syncthreads();
        if (k0 + 64 < DD) {
            pa0 = *(const float4*)(Ab + (size_t)(rowBase + am) * lda + k0 + 64 + ak);
            pa1 = *(const float4*)(Ab + (size_t)(rowBase + am + 16) * lda + k0 + 64 + ak);
            pb0 = *(const float4*)(Bb + (size_t)(bk + k0 + 64) * ldb + colBase + bn);
            pb1 = *(const float4*)(Bb + (size_t)(bk + 32 + k0 + 64) * ldb + colBase + bn);
        }
#pragma unroll
        for (int kk = 0; kk < 64; ++kk) {
            float2 a2 = *(const float2*)(&As[kk * 38 + (ty << 1)]);
            float2 b2 = *(const float2*)(&Bs[kk * 40 + (tx << 1)]);
            acc[0][0] = fmaf(a2.x, b2.x, acc[0][0]);
            acc[0][1] = fmaf(a2.x, b2.y, acc[0][1]);
            acc[1][0] = fmaf(a2.y, b2.x, acc[1][0]);
            acc[1][1] = fmaf(a2.y, b2.y, acc[1][1]);
        }
        __syncthreads();
    }
}

// N1: acc = K@K. A2 = cs^2*acc ; Bop = 2I + 2cs*K + 2cs^2*acc ; Zb0 = bf16(z0)
__global__ void __launch_bounds__(256)
n1_kernel(const float* __restrict__ K, const float* __restrict__ log_dt,
          const float* __restrict__ z0, float* __restrict__ A2,
          float* __restrict__ Bop, unsigned short* __restrict__ Zb0) {
    const float cs = 0.5f * expf(log_dt[0]);
    {
        int b = ((blockIdx.y * 8 + blockIdx.x) * 256 + threadIdx.x) * 4;
        uint2 w;
        w.x = pack2bf(z0[b], z0[b + 1]);
        w.y = pack2bf(z0[b + 2], z0[b + 3]);
        *(uint2*)(Zb0 + b) = w;
    }
    float acc[2][2];
    const int rowBase = blockIdx.y << 5, colBase = blockIdx.x << 5;
    g32_core(K, DD, K, DD, rowBase, colBase, acc);
    const float cs2 = cs * cs;
    const int r0 = rowBase + ((threadIdx.x >> 4) << 1);
    const int c0 = colBase + ((threadIdx.x & 15) << 1);
#pragma unroll
    for (int i = 0; i < 2; ++i) {
        int r = r0 + i;
        float e0 = K[(size_t)r * DD + c0], e1 = K[(size_t)r * DD + c0 + 1];
        float p0 = cs2 * acc[i][0], p1 = cs2 * acc[i][1];
        *(float2*)(A2 + (size_t)r * DD + c0) = (float2){p0, p1};
        float2 w;
        w.x = 2.f * p0 + 2.f * cs * e0 + (r == c0 ? 2.f : 0.f);
        w.y = 2.f * p1 + 2.f * cs * e1 + (r == c0 + 1 ? 2.f : 0.f);
        *(float2*)(Bop + (size_t)r * DD + c0) = w;
    }
}

// N2: E = Kd - I = A2@Bop + 2cs*K
__global__ void __launch_bounds__(256)
n2_kernel(const float* __restrict__ A2, const float* __restrict__ Bop,
          const float* __restrict__ K, const float* __restrict__ log_dt,
          float* __restrict__ E) {
    const float cs = 0.5f * expf(log_dt[0]);
    float acc[2][2];
    const int rowBase = blockIdx.y << 5, colBase = blockIdx.x << 5;
    g32_core(A2, DD, Bop, DD, rowBase, colBase, acc);
    const int r0 = rowBase + ((threadIdx.x >> 4) << 1);
    const int c0 = colBase + ((threadIdx.x & 15) << 1);
#pragma unroll
    for (int i = 0; i < 2; ++i) {
        int r = r0 + i;
        float e0 = K[(size_t)r * DD + c0], e1 = K[(size_t)r * DD + c0 + 1];
        float2 v;
        v.x = acc[i][0] + 2.f * cs * e0;
        v.y = acc[i][1] + 2.f * cs * e1;
        *(float2*)(E + (size_t)r * DD + c0) = v;
    }
}

// Generic batched 256^3 f32 GEMM for E-power stages 1-2.
__global__ void __launch_bounds__(256)
gpow_kernel(const float* __restrict__ A, const float* __restrict__ B,
            float* __restrict__ C, long long sA, long long sB, long long sC) {
    float acc[2][2];
    const int rowBase = blockIdx.y << 5, colBase = blockIdx.x << 5;
    g32_core(A + blockIdx.z * sA, DD, B + blockIdx.z * sB, DD, rowBase, colBase, acc);
    float* Cb = C + blockIdx.z * sC;
    const int r0 = rowBase + ((threadIdx.x >> 4) << 1);
    const int c0 = colBase + ((threadIdx.x & 15) << 1);
#pragma unroll
    for (int i = 0; i < 2; ++i) {
        int r = r0 + i;
        *(float2*)(Cb + (size_t)r * DD + c0) = (float2){acc[i][0], acc[i][1]};
    }
}

// E-power stage 3 (batch 4): E5=E2@E3, E6=E3@E3, E7=E3@E4, E8=E4@E4
__global__ void __launch_bounds__(256)
gpow4_kernel(float* __restrict__ Epow) {
    static const int sa[4] = {1, 2, 2, 3};
    static const int sb[4] = {2, 2, 3, 3};
    static const int sc[4] = {4, 5, 6, 7};
    const int z = blockIdx.z;
    float acc[2][2];
    const int rowBase = blockIdx.y << 5, colBase = blockIdx.x << 5;
    g32_core(Epow + (size_t)sa[z] * MATF, DD, Epow + (size_t)sb[z] * MATF, DD,
             rowBase, colBase, acc);
    float* Cb = Epow + (size_t)sc[z] * MATF;
    const int r0 = rowBase + ((threadIdx.x >> 4) << 1);
    const int c0 = colBase + ((threadIdx.x & 15) << 1);
#pragma unroll
    for (int i = 0; i < 2; ++i) {
        int r = r0 + i;
        *(float2*)(Cb + (size_t)r * DD + c0) = (float2){acc[i][0], acc[i][1]};
    }
}

// comb: M_j = (I+E)^j = I + sum_{m<=8} C(j,m)E^m, j=1..32 -> bf16 MTb[j][c][k],
// plus f32 W1=(I+E)^32, W2=(I+E)^64, W3=(I+E)^96.
__global__ void __launch_bounds__(256)
comb_kernel(const float* __restrict__ Epow, unsigned short* __restrict__ MTb,
            float* __restrict__ W1, float* __restrict__ W2,
            float* __restrict__ W3) {
    __shared__ float tle[8][32][33];
    const int tid = threadIdx.x;
    const int k0 = blockIdx.y << 5, c0 = blockIdx.x << 5;
    const int ltx = tid & 31, lty = tid >> 5;
#pragma unroll
    for (int m = 0; m < 8; ++m)
#pragma unroll
        for (int it = 0; it < 4; ++it) {
            int k = lty + (it << 3);
            tle[m][ltx][k] =
                Epow[(size_t)m * MATF + (size_t)(k0 + k) * DD + c0 + ltx];
        }
    __syncthreads();

    const int c = tid >> 3;
    const int kb = (tid & 7) << 2;
    float em[8][4];
#pragma unroll
    for (int m = 0; m < 8; ++m)
#pragma unroll
        for (int u = 0; u < 4; ++u) em[m][u] = tle[m][c][kb + u];

    float diag[4];
#pragma unroll
    for (int u = 0; u < 4; ++u)
        diag[u] = ((k0 + kb + u) == (c0 + c)) ? 1.f : 0.f;

    float w32[4];
    for (int j = 1; j <= 32; ++j) {
        float val[4] = {diag[0], diag[1], diag[2], diag[3]};
        long long coef = 1;
#pragma unroll
        for (int m = 1; m <= 8; ++m) {
            coef = coef * (j - m + 1) / m;
            float cf = (float)(coef < 0 ? 0 : coef);
#pragma unroll
            for (int u = 0; u < 4; ++u) val[u] = fmaf(cf, em[m - 1][u], val[u]);
        }
        uint2 w;
        w.x = pack2bf(val[0], val[1]);
        w.y = pack2bf(val[2], val[3]);
        *(uint2*)(MTb + (size_t)(j - 1) * MATF + (size_t)(c0 + c) * DD + k0 + kb) = w;
        if (j == 32) {
            w32[0] = val[0]; w32[1] = val[1]; w32[2] = val[2]; w32[3] = val[3];
        }
    }
    float w64[4] = {diag[0], diag[1], diag[2], diag[3]};
    float w96[4] = {diag[0], diag[1], diag[2], diag[3]};
    {
        double c64 = 1.0, c96 = 1.0;
#pragma unroll
        for (int m = 1; m <= 8; ++m) {
            c64 = c64 * (double)(64 - m + 1) / (double)m;
            c96 = c96 * (double)(96 - m + 1) / (double)m;
            float f64 = (float)c64, f96 = (float)c96;
#pragma unroll
            for (int u = 0; u < 4; ++u) {
                w64[u] = fmaf(f64, em[m - 1][u], w64[u]);
                w96[u] = fmaf(f96, em[m - 1][u], w96[u]);
            }
        }
    }
    float* tw = &tle[0][0][0];
    const int wk = tid >> 3, wc = (tid & 7) << 2;
    float* Wd[3] = {W1, W2, W3};
    float* Ws[3] = {w32, w64, w96};
#pragma unroll
    for (int p = 0; p < 3; ++p) {
        __syncthreads();
#pragma unroll
        for (int u = 0; u < 4; ++u) tw[(kb + u) * 33 + c] = Ws[p][u];
        __syncthreads();
        float4 v = {tw[wk * 33 + wc], tw[wk * 33 + wc + 1],
                    tw[wk * 33 + wc + 2], tw[wk * 33 + wc + 3]};
        *(float4*)(Wd[p] + (size_t)(k0 + wk) * DD + c0 + wc) = v;
    }
}

// 3-level checkpoint scan, contiguous operands (proven r12).
__global__ void __launch_bounds__(256)
scan3_kernel(const float* __restrict__ z0, float* __restrict__ Zf,
             const float* __restrict__ W1, const float* __restrict__ W2,
             const float* __restrict__ W3, float* __restrict__ Wtab,
             unsigned short* __restrict__ Zb, int level) {
    static const signed char JA[3][7] = {{0, 0, 0, 17, 18, 0, 0},
                                         {0, 1, 2, 3, 2, 3, 20},
                                         {4, 5, 0, 1, 2, 3, 0}};
    static const signed char JB[3][7] = {{0, 1, 2, 1, 2, 0, 0},
                                         {3, 3, 3, 3, 4, 4, 4},
                                         {4, 4, 5, 5, 5, 5, 0}};
    static const signed char JD[3][7] = {{1, 2, 3, 19, 20, 0, 0},
                                         {4, 5, 6, 7, 8, 9, 21},
                                         {10, 11, 12, 13, 14, 15, 0}};
    const float* Wp[6] = {W1, W2, W3, Wtab, Wtab + MATF, Wtab + 2 * (size_t)MATF};
    const int jz = blockIdx.z;
    const int a = JA[level][jz], b = JB[level][jz], d = JD[level][jz];

    const float* Asrc;
    if (a == 0) Asrc = z0;
    else if (a < 16) Asrc = Zf + (size_t)a * MATF;
    else Asrc = Wp[a - 16];

    float acc[2][2];
    const int rowBase = blockIdx.y << 5, colBase = blockIdx.x << 5;
    g32_core(Asrc, DD, Wp[b], DD, rowBase, colBase, acc);

    const int r0 = rowBase + ((threadIdx.x >> 4) << 1);
    const int c0 = colBase + ((threadIdx.x & 15) << 1);
    if (d < 16) {
        float* Zo32 = Zf + (size_t)d * MATF;
        unsigned short* Zo = Zb + (size_t)d * MATF;
#pragma unroll
        for (int ii = 0; ii < 2; ++ii) {
            int r = r0 + ii;
            float2 v = {acc[ii][0], acc[ii][1]};
            *(float2*)(Zo32 + (size_t)r * DD + c0) = v;
            *(unsigned*)(Zo + (size_t)r * DD + c0) = pack2bf(v.x, v.y);
        }
    } else {
        float* Cb = Wtab + (size_t)(d - 19) * MATF;
#pragma unroll
        for (int ii = 0; ii < 2; ++ii) {
            int r = r0 + ii;
            *(float2*)(Cb + (size_t)r * DD + c0) = (float2){acc[ii][0], acc[ii][1]};
        }
    }
}

// Batched bf16 MFMA fill (proven r8/r10 core), all 512 timesteps.
// r13: j-MAJOR job order -- zz = (j-1)*16 + i, so concurrent blocks share a
// small MTb window (~16 tables, L2-resident) instead of cycling all 32.
__global__ void __launch_bounds__(256)
fill_kernel(const unsigned short* __restrict__ Zb,
            const unsigned short* __restrict__ MTb,
            float* __restrict__ out) {
    __shared__ __align__(16) char pool[32768];
    const int zz = blockIdx.z;
    const int i = zz & 15;
    const int j = (zz >> 4) + 1;
    const int t = i * 32 + j - 1;
    const unsigned short* Zt = Zb + (size_t)i * MATF;
    const unsigned short* MT = MTb + (size_t)(j - 1) * MATF;

    const int tid = threadIdx.x;
    const int lane = tid & 63, wid = tid >> 6;
    const int rowBase = blockIdx.y * 128, colBase = blockIdx.x * 128;
    const int wr = (wid >> 1) * 64, wc = (wid & 1) * 64;

    int rowq[4], skq[4], ldsb[4];
#pragma unroll
    for (int q = 0; q < 4; ++q) {
        int c = q * 256 + wid * 64 + lane;
        int row = c >> 3;
        rowq[q] = row;
        skq[q] = ((c ^ (row & 7)) & 7) << 3;
        ldsb[q] = (q * 256 + wid * 64) << 4;
    }

    f32x4 acc[4][4];
#pragma unroll
    for (int a = 0; a < 4; ++a)
#pragma unroll
        for (int b = 0; b < 4; ++b) acc[a][b] = (f32x4){0.f, 0.f, 0.f, 0.f};

    auto stage = [&](int k0) {
#pragma unroll
        for (int q = 0; q < 4; ++q) {
            GLD16(Zt + (size_t)(rowBase + rowq[q]) * DD + k0 + skq[q], pool + ldsb[q]);
            GLD16(MT + (size_t)(colBase + rowq[q]) * DD + k0 + skq[q],
                  pool + 16384 + ldsb[q]);
        }
    };

    stage(0);
    for (int r = 0; r < 4; ++r) {
        __syncthreads();
        const char* asb = pool;
        const char* bsb = pool + 16384;
#pragma unroll
        for (int ks = 0; ks < 2; ++ks) {
            bf16x8 af[4], bg[4];
            const int kk = ks * 32 + (lane >> 4) * 8;
#pragma unroll
            for (int f = 0; f < 4; ++f) {
                int rr = wr + f * 16 + (lane & 15);
                af[f] = *(const bf16x8*)(asb + ((rr * 128 + kk * 2) ^ ((rr & 7) << 4)));
                int cc = wc + f * 16 + (lane & 15);
                bg[f] = *(const bf16x8*)(bsb + ((cc * 128 + kk * 2) ^ ((cc & 7) << 4)));
            }
#pragma unroll
            for (int fr = 0; fr < 4; ++fr)
#pragma unroll
                for (int fc = 0; fc < 4; ++fc)
                    acc[fr][fc] = __builtin_amdgcn_mfma_f32_16x16x32_bf16(
                        af[fr], bg[fc], acc[fr][fc], 0, 0, 0);
        }
        __syncthreads();
        if (r < 3) stage((r + 1) * 64);
    }

    float* Cs = (float*)pool;
    float* C = out + (size_t)t * DD;
#pragma unroll
    for (int hp = 0; hp < 2; ++hp) {
        __syncthreads();
        if (wr == hp * 64) {
#pragma unroll
            for (int fr = 0; fr < 4; ++fr) {
#pragma unroll
                for (int fc = 0; fc < 4; ++fc) {
                    int ccol = wc + fc * 16 + (lane & 15);
#pragma unroll
                    for (int ii = 0; ii < 4; ++ii) {
                        int lr = fr * 16 + ((lane >> 4) << 2) + ii;
                        int csw = ccol ^ (((lr >> 2) & 1) << 4);
                        Cs[lr * 128 + csw] = acc[fr][fc][ii];
                    }
                }
            }
        }
        __syncthreads();
#pragma unroll
        for (int it = 0; it < 8; ++it) {
            int chunk = it * 256 + tid;
            int row = chunk >> 5;
            int c4 = (chunk & 31) << 2;
            int csw = c4 ^ (((row >> 2) & 1) << 4);
            float4 v = *(const float4*)(Cs + row * 128 + csw);
            *(float4*)(C + (size_t)(rowBase + hp * 64 + row) * LDT + colBase + c4) = v;
        }
    }
}

// ---------------- fallback (tiny ws): proven g32 chain ----------------------
__global__ void prep_kernel(const float* __restrict__ K,
                            const float* __restrict__ log_dt,
                            float* __restrict__ A) {
    int idx = blockIdx.x * blockDim.x + threadIdx.x;
    A[idx] = 0.5f * expf(log_dt[0]) * K[idx];
}

template <int EPI>
__global__ void __launch_bounds__(256)
g32_kernel(const float* A, const float* B, float* C, const float* E, float* C2,
           int lda, int ldb, int ldc, long long sA, long long sB, long long sC) {
    float acc[2][2];
    const int rowBase = blockIdx.y << 5, colBase = blockIdx.x << 5;
    g32_core(A + blockIdx.z * sA, lda, B + blockIdx.z * sB, ldb, rowBase, colBase, acc);
    float* Cb = C + blockIdx.z * sC;
    const int r0 = rowBase + ((threadIdx.x >> 4) << 1);
    const int c0 = colBase + ((threadIdx.x & 15) << 1);
#pragma unroll
    for (int i = 0; i < 2; ++i) {
        int r = r0 + i;
        float2 v;
        if (EPI == 2) {
            float e0 = E[(size_t)r * DD + c0], e1 = E[(size_t)r * DD + c0 + 1];
            v.x = acc[i][0] + 2.f * e0 + (r == c0 ? 1.f : 0.f);
            v.y = acc[i][1] + 2.f * e1 + (r == c0 + 1 ? 1.f : 0.f);
        } else {
            v.x = acc[i][0];
            v.y = acc[i][1];
        }
        *(float2*)(Cb + (size_t)r * ldc + c0) = v;
        if (EPI == 1) {
            float e0 = E[(size_t)r * DD + c0], e1 = E[(size_t)r * DD + c0 + 1];
            float2 w;
            w.x = 2.f * acc[i][0] + 2.f * e0 + (r == c0 ? 2.f : 0.f);
            w.y = 2.f * acc[i][1] + 2.f * e1 + (r == c0 + 1 ? 2.f : 0.f);
            *(float2*)(C2 + (size_t)r * DD + c0) = w;
        }
    }
}

// ---------------- launch ----------------------------------------------------
extern "C" void kernel_launch(void* const* d_in, const int* in_sizes, int n_in,
                              void* d_out, int out_size, void* d_ws, size_t ws_size,
                              hipStream_t stream) {
    const float* z0 = (const float*)d_in[0];
    const float* Kmat = (const float*)d_in[1];
    const float* log_dt = (const float*)d_in[2];
    float* out = (float*)d_out;

    dim3 blk(256);

    // ws: A2 | Bop | Epow[8] | W1 | W2 | W3 | Wtab[3] | Zf[16] f32
    //     | MTb[32] | Zb[16] bf16
    float* A2 = (float*)d_ws;
    float* Bop = A2 + MATF;
    float* Epow = Bop + MATF;
    float* W1 = Epow + (size_t)8 * MATF;
    float* W2 = W1 + MATF;
    float* W3 = W2 + MATF;
    float* Wtab = W3 + MATF;
    float* Zf = Wtab + (size_t)3 * MATF;
    unsigned short* MTb = (unsigned short*)(Zf + (size_t)16 * MATF);
    unsigned short* Zb = MTb + (size_t)32 * MATF;
    const size_t need = (size_t)32 * MATF * 4 + (size_t)48 * MATF * 2;

    if (ws_size >= need) {
        dim3 g(8, 8, 1);
        // Neumann order-4 -> E = Kd - I (2 launches)
        n1_kernel<<<g, blk, 0, stream>>>(Kmat, log_dt, z0, A2, Bop, Zb);
        n2_kernel<<<g, blk, 0, stream>>>(A2, Bop, Kmat, log_dt, Epow);

        // E-powers: E2 ; {E3,E4} ; {E5,E6,E7,E8}
        gpow_kernel<<<g, blk, 0, stream>>>(Epow, Epow, Epow + MATF, 0, 0, 0);
        gpow_kernel<<<dim3(8, 8, 2), blk, 0, stream>>>(
            Epow, Epow + MATF, Epow + 2 * (size_t)MATF, MATF, 0, MATF);
        gpow4_kernel<<<dim3(8, 8, 4), blk, 0, stream>>>(Epow);

        // All 32 M-tables (bf16-T) + W1/W2/W3 f32, one launch
        comb_kernel<<<g, blk, 0, stream>>>(Epow, MTb, W1, W2, W3);

        // checkpoint scan: 3 batched levels, contiguous operands
        const int njobs[3] = {5, 7, 6};
        for (int s = 0; s < 3; ++s)
            scan3_kernel<<<dim3(8, 8, njobs[s]), blk, 0, stream>>>(
                z0, Zf, W1, W2, W3, Wtab, Zb, s);

        // ALL 512 timesteps, j-major order
        fill_kernel<<<dim3(2, 2, 512), blk, 0, stream>>>(Zb, MTb, out);
        return;
    }

    // Minimal fallback (tiny ws): Kd then 512 chained GEMMs (f32, proven core).
    float* A = (float*)d_ws;
    float* A2f = A + MATF;
    float* Bopf = A2f + MATF;
    float* Kd = Bopf + MATF;
    prep_kernel<<<MATF / 256, blk, 0, stream>>>(Kmat, log_dt, A);
    dim3 g(8, 8, 1);
    g32_kernel<1><<<g, blk, 0, stream>>>(A, A, A2f, A, Bopf, DD, DD, DD, 0, 0, 0);
    g32_kernel<2><<<g, blk, 0, stream>>>(A2f, Bopf, Kd, A, (float*)0, DD, DD, DD, 0, 0, 0);
    for (int t = 0; t < TT; ++t) {
        const float* Ain = (t == 0) ? z0 : out + (size_t)(t - 1) * DD;
        int lda = (t == 0) ? DD : (int)LDT;
        g32_kernel<0><<<g, blk, 0, stream>>>(Ain, Kd, out + (size_t)t * DD,
                                             (const float*)0, (float*)0,
                                             lda, DD, (int)LDT, 0, 0, 0);
    }
}

// Round 14
// 103.334 us; speedup vs baseline: 1.2083x; 1.1132x over previous
//
#include <hip/hip_runtime.h>

// Koopman bilinear rollout: preds[b,t,d] = (z0 @ Kd^{t+1})[b,d], D=B=256, T=512.
// r14: DIRECT K-power series -- Kd^j = (I+A)^j(I-A)^{-j}, A = cs*K:
//   M_j = I + sum_{m<=8} g_m^(j) cs^m K^m,  g_m^(j) = sum_p C(j,p)C(j+m-p-1,m-p).
// Chain: K^2 ; {K^3,K^4} ; {K^5..K^8} ; comb (all 32 bf16-T M-tables +
// W1/W2/W3 = Kd^{32,64,96} f32 + bf16(z0)) ; 3-level scan ; fill. 8 launches,
// 7 dependent stages (was 9 -- n1/n2 Neumann eliminated).
// Truncation: M_j rel ~1e-10, W3 rel ~3e-4 (-> <0.15 abs on outputs, vs 2.0
// bf16 floor). Scan + fill byte-identical to proven r12/r13.
// DEAD ENDS (do not retry): persistent kernel + grid barrier (r5 392us,
// r7 289us); 256x256 fill tile (r11, -5us); fill j-major was ~neutral (r13).

#define DD 256
#define TT 512
#define MATF (DD * DD)
#define LDT ((size_t)TT * (size_t)DD)

typedef __attribute__((ext_vector_type(8))) short bf16x8;
typedef __attribute__((ext_vector_type(4))) float f32x4;

#define GLD16(g, l)                                                  \
    __builtin_amdgcn_global_load_lds(                                \
        (const __attribute__((address_space(1))) void*)(g),          \
        (__attribute__((address_space(3))) void*)(l), 16, 0, 0)

static __device__ __forceinline__ unsigned short f2bf(float f) {
    unsigned int u = __float_as_uint(f);
    u += 0x7fffu + ((u >> 16) & 1u);
    return (unsigned short)(u >> 16);
}
static __device__ __forceinline__ unsigned pack2bf(float a, float b) {
    return (unsigned)f2bf(a) | ((unsigned)f2bf(b) << 16);
}

// ---- 32x32-tile f32 GEMM core: 256 threads, K=256, K_BLK=64, reg prefetch ----
__device__ __forceinline__ void g32_core(const float* __restrict__ Ab, int lda,
                                         const float* __restrict__ Bb, int ldb,
                                         int rowBase, int colBase, float acc[2][2]) {
    __shared__ __align__(16) float As[64 * 38];
    __shared__ __align__(16) float Bs[64 * 40];
    const int tid = threadIdx.x;
    const int tx = tid & 15, ty = tid >> 4;
    const int am = tid >> 4;
    const int ak = (tid & 15) << 2;
    const int bk = tid >> 3;
    const int bn = (tid & 7) << 2;

    acc[0][0] = acc[0][1] = acc[1][0] = acc[1][1] = 0.f;

    float4 pa0 = *(const float4*)(Ab + (size_t)(rowBase + am) * lda + ak);
    float4 pa1 = *(const float4*)(Ab + (size_t)(rowBase + am + 16) * lda + ak);
    float4 pb0 = *(const float4*)(Bb + (size_t)bk * ldb + colBase + bn);
    float4 pb1 = *(const float4*)(Bb + (size_t)(bk + 32) * ldb + colBase + bn);

    for (int k0 = 0; k0 < DD; k0 += 64) {
        As[(ak + 0) * 38 + am] = pa0.x;
        As[(ak + 1) * 38 + am] = pa0.y;
        As[(ak + 2) * 38 + am] = pa0.z;
        As[(ak + 3) * 38 + am] = pa0.w;
        As[(ak + 0) * 38 + am + 16] = pa1.x;
        As[(ak + 1) * 38 + am + 16] = pa1.y;
        As[(ak + 2) * 38 + am + 16] = pa1.z;
        As[(ak + 3) * 38 + am + 16] = pa1.w;
        *(float4*)(&Bs[bk * 40 + bn]) = pb0;
        *(float4*)(&Bs[(bk + 32) * 40 + bn]) = pb1;
        __syncthreads();
        if (k0 + 64 < DD) {
            pa0 = *(const float4*)(Ab + (size_t)(rowBase + am) * lda + k0 + 64 + ak);
            pa1 = *(const float4*)(Ab + (size_t)(rowBase + am + 16) * lda + k0 + 64 + ak);
            pb0 = *(const float4*)(Bb + (size_t)(bk + k0 + 64) * ldb + colBase + bn);
            pb1 = *(const float4*)(Bb + (size_t)(bk + 32 + k0 + 64) * ldb + colBase + bn);
        }
#pragma unroll
        for (int kk = 0; kk < 64; ++kk) {
            float2 a2 = *(const float2*)(&As[kk * 38 + (ty << 1)]);
            float2 b2 = *(const float2*)(&Bs[kk * 40 + (tx << 1)]);
            acc[0][0] = fmaf(a2.x, b2.x, acc[0][0]);
            acc[0][1] = fmaf(a2.x, b2.y, acc[0][1]);
            acc[1][0] = fmaf(a2.y, b2.x, acc[1][0]);
            acc[1][1] = fmaf(a2.y, b2.y, acc[1][1]);
        }
        __syncthreads();
    }
}

// p1: Pw[0] = K (copy, 4 elems/thread) ; Pw[1] = K@K
__global__ void __launch_bounds__(256)
p1_kernel(const float* __restrict__ K, float* __restrict__ Pw) {
    {
        int b = ((blockIdx.y * 8 + blockIdx.x) * 256 + threadIdx.x) * 4;
        *(float4*)(Pw + b) = *(const float4*)(K + b);
    }
    float acc[2][2];
    const int rowBase = blockIdx.y << 5, colBase = blockIdx.x << 5;
    g32_core(K, DD, K, DD, rowBase, colBase, acc);
    float* Cb = Pw + MATF;
    const int r0 = rowBase + ((threadIdx.x >> 4) << 1);
    const int c0 = colBase + ((threadIdx.x & 15) << 1);
#pragma unroll
    for (int i = 0; i < 2; ++i) {
        int r = r0 + i;
        *(float2*)(Cb + (size_t)r * DD + c0) = (float2){acc[i][0], acc[i][1]};
    }
}

// Generic batched 256^3 f32 GEMM (stage 2): {K^3=K@K^2, K^4=K^2@K^2}
__global__ void __launch_bounds__(256)
gpow_kernel(const float* __restrict__ A, const float* __restrict__ B,
            float* __restrict__ C, long long sA, long long sB, long long sC) {
    float acc[2][2];
    const int rowBase = blockIdx.y << 5, colBase = blockIdx.x << 5;
    g32_core(A + blockIdx.z * sA, DD, B + blockIdx.z * sB, DD, rowBase, colBase, acc);
    float* Cb = C + blockIdx.z * sC;
    const int r0 = rowBase + ((threadIdx.x >> 4) << 1);
    const int c0 = colBase + ((threadIdx.x & 15) << 1);
#pragma unroll
    for (int i = 0; i < 2; ++i) {
        int r = r0 + i;
        *(float2*)(Cb + (size_t)r * DD + c0) = (float2){acc[i][0], acc[i][1]};
    }
}

// stage 3 (batch 4): K^5=K^2@K^3, K^6=K^3@K^3, K^7=K^3@K^4, K^8=K^4@K^4
// (indices relative to Pw base: Pw[m-1] = K^m)
__global__ void __launch_bounds__(256)
gpow4_kernel(float* __restrict__ Pw) {
    static const int sa[4] = {1, 2, 2, 3};
    static const int sb[4] = {2, 2, 3, 3};
    static const int sc[4] = {4, 5, 6, 7};
    const int z = blockIdx.z;
    float acc[2][2];
    const int rowBase = blockIdx.y << 5, colBase = blockIdx.x << 5;
    g32_core(Pw + (size_t)sa[z] * MATF, DD, Pw + (size_t)sb[z] * MATF, DD,
             rowBase, colBase, acc);
    float* Cb = Pw + (size_t)sc[z] * MATF;
    const int r0 = rowBase + ((threadIdx.x >> 4) << 1);
    const int c0 = colBase + ((threadIdx.x & 15) << 1);
#pragma unroll
    for (int i = 0; i < 2; ++i) {
        int r = r0 + i;
        *(float2*)(Cb + (size_t)r * DD + c0) = (float2){acc[i][0], acc[i][1]};
    }
}

// comb: M_j = I + sum_{m=1..8} g_m^(j) cs^m K^m  (j=1..32) -> bf16 MTb[j][c][k]
// + f32 W1/W2/W3 = Kd^{32,64,96} + Zb0 = bf16(z0).
// Coefficients g_m^(j) = sum_p C(j,p) C(j+m-p-1, m-p), exact in double
// (largest product ~1.2e13 < 2^53), folded with cs^m; 34 rows in LDS.
__global__ void __launch_bounds__(256)
comb_kernel(const float* __restrict__ Pw, const float* __restrict__ log_dt,
            const float* __restrict__ z0, unsigned short* __restrict__ MTb,
            float* __restrict__ W1, float* __restrict__ W2,
            float* __restrict__ W3, unsigned short* __restrict__ Zb0) {
    __shared__ float tle[8][32][33];
    __shared__ float gtab[34][8];
    const int tid = threadIdx.x;
    const int k0 = blockIdx.y << 5, c0 = blockIdx.x << 5;
    const float csf = 0.5f * expf(log_dt[0]);

    // fold prep: bf16(z0), 4 elems/thread
    {
        int b = ((blockIdx.y * 8 + blockIdx.x) * 256 + tid) * 4;
        uint2 w;
        w.x = pack2bf(z0[b], z0[b + 1]);
        w.y = pack2bf(z0[b + 2], z0[b + 3]);
        *(uint2*)(Zb0 + b) = w;
    }

    // coefficient table: rows 0..31 -> j=1..32 ; row 32 -> j=64 ; row 33 -> j=96
    if (tid < 34) {
        int j = (tid < 32) ? (tid + 1) : ((tid == 32) ? 64 : 96);
        double b[9], cq[9];
        b[0] = 1.0;
        cq[0] = 1.0;
#pragma unroll
        for (int p = 1; p <= 8; ++p) {
            b[p] = b[p - 1] * (double)(j - p + 1) / (double)p;   // C(j,p)
            cq[p] = cq[p - 1] * (double)(j + p - 1) / (double)p; // C(j+p-1,p)
        }
        double csm = (double)csf;
#pragma unroll
        for (int m = 1; m <= 8; ++m) {
            double s = 0.0;
#pragma unroll
            for (int p = 0; p <= 8; ++p)
                if (p <= m) s += b[p] * cq[m - p];
            gtab[tid][m - 1] = (float)(s * csm);
            csm *= (double)csf;
        }
    }

    const int ltx = tid & 31, lty = tid >> 5;
#pragma unroll
    for (int m = 0; m < 8; ++m)
#pragma unroll
        for (int it = 0; it < 4; ++it) {
            int k = lty + (it << 3);
            tle[m][ltx][k] =
                Pw[(size_t)m * MATF + (size_t)(k0 + k) * DD + c0 + ltx];
        }
    __syncthreads();

    const int c = tid >> 3;
    const int kb = (tid & 7) << 2;
    float em[8][4];
#pragma unroll
    for (int m = 0; m < 8; ++m)
#pragma unroll
        for (int u = 0; u < 4; ++u) em[m][u] = tle[m][c][kb + u];

    float diag[4];
#pragma unroll
    for (int u = 0; u < 4; ++u)
        diag[u] = ((k0 + kb + u) == (c0 + c)) ? 1.f : 0.f;

    float w32[4];
    for (int j = 1; j <= 32; ++j) {
        float val[4] = {diag[0], diag[1], diag[2], diag[3]};
        const float* gj = gtab[j - 1];
#pragma unroll
        for (int m = 0; m < 8; ++m)
#pragma unroll
            for (int u = 0; u < 4; ++u) val[u] = fmaf(gj[m], em[m][u], val[u]);
        uint2 w;
        w.x = pack2bf(val[0], val[1]);
        w.y = pack2bf(val[2], val[3]);
        *(uint2*)(MTb + (size_t)(j - 1) * MATF + (size_t)(c0 + c) * DD + k0 + kb) = w;
        if (j == 32) {
            w32[0] = val[0]; w32[1] = val[1]; w32[2] = val[2]; w32[3] = val[3];
        }
    }
    float w64[4] = {diag[0], diag[1], diag[2], diag[3]};
    float w96[4] = {diag[0], diag[1], diag[2], diag[3]};
#pragma unroll
    for (int m = 0; m < 8; ++m)
#pragma unroll
        for (int u = 0; u < 4; ++u) {
            w64[u] = fmaf(gtab[32][m], em[m][u], w64[u]);
            w96[u] = fmaf(gtab[33][m], em[m][u], w96[u]);
        }

    // three LDS-transpose passes -> coalesced f32 stores in [k][c] layout
    float* tw = &tle[0][0][0];
    const int wk = tid >> 3, wc = (tid & 7) << 2;
    float* Wd[3] = {W1, W2, W3};
    float* Ws[3] = {w32, w64, w96};
#pragma unroll
    for (int p = 0; p < 3; ++p) {
        __syncthreads();
#pragma unroll
        for (int u = 0; u < 4; ++u) tw[(kb + u) * 33 + c] = Ws[p][u];
        __syncthreads();
        float4 v = {tw[wk * 33 + wc], tw[wk * 33 + wc + 1],
                    tw[wk * 33 + wc + 2], tw[wk * 33 + wc + 3]};
        *(float4*)(Wd[p] + (size_t)(k0 + wk) * DD + c0 + wc) = v;
    }
}

// 3-level checkpoint scan, contiguous operands (proven r12/r13).
__global__ void __launch_bounds__(256)
scan3_kernel(const float* __restrict__ z0, float* __restrict__ Zf,
             const float* __restrict__ W1, const float* __restrict__ W2,
             const float* __restrict__ W3, float* __restrict__ Wtab,
             unsigned short* __restrict__ Zb, int level) {
    static const signed char JA[3][7] = {{0, 0, 0, 17, 18, 0, 0},
                                         {0, 1, 2, 3, 2, 3, 20},
                                         {4, 5, 0, 1, 2, 3, 0}};
    static const signed char JB[3][7] = {{0, 1, 2, 1, 2, 0, 0},
                                         {3, 3, 3, 3, 4, 4, 4},
                                         {4, 4, 5, 5, 5, 5, 0}};
    static const signed char JD[3][7] = {{1, 2, 3, 19, 20, 0, 0},
                                         {4, 5, 6, 7, 8, 9, 21},
                                         {10, 11, 12, 13, 14, 15, 0}};
    const float* Wp[6] = {W1, W2, W3, Wtab, Wtab + MATF, Wtab + 2 * (size_t)MATF};
    const int jz = blockIdx.z;
    const int a = JA[level][jz], b = JB[level][jz], d = JD[level][jz];

    const float* Asrc;
    if (a == 0) Asrc = z0;
    else if (a < 16) Asrc = Zf + (size_t)a * MATF;
    else Asrc = Wp[a - 16];

    float acc[2][2];
    const int rowBase = blockIdx.y << 5, colBase = blockIdx.x << 5;
    g32_core(Asrc, DD, Wp[b], DD, rowBase, colBase, acc);

    const int r0 = rowBase + ((threadIdx.x >> 4) << 1);
    const int c0 = colBase + ((threadIdx.x & 15) << 1);
    if (d < 16) {
        float* Zo32 = Zf + (size_t)d * MATF;
        unsigned short* Zo = Zb + (size_t)d * MATF;
#pragma unroll
        for (int ii = 0; ii < 2; ++ii) {
            int r = r0 + ii;
            float2 v = {acc[ii][0], acc[ii][1]};
            *(float2*)(Zo32 + (size_t)r * DD + c0) = v;
            *(unsigned*)(Zo + (size_t)r * DD + c0) = pack2bf(v.x, v.y);
        }
    } else {
        float* Cb = Wtab + (size_t)(d - 19) * MATF;
#pragma unroll
        for (int ii = 0; ii < 2; ++ii) {
            int r = r0 + ii;
            *(float2*)(Cb + (size_t)r * DD + c0) = (float2){acc[ii][0], acc[ii][1]};
        }
    }
}

// Batched bf16 MFMA fill (proven r8/r10/r13), all 512 timesteps, j-major.
__global__ void __launch_bounds__(256)
fill_kernel(const unsigned short* __restrict__ Zb,
            const unsigned short* __restrict__ MTb,
            float* __restrict__ out) {
    __shared__ __align__(16) char pool[32768];
    const int zz = blockIdx.z;
    const int i = zz & 15;
    const int j = (zz >> 4) + 1;
    const int t = i * 32 + j - 1;
    const unsigned short* Zt = Zb + (size_t)i * MATF;
    const unsigned short* MT = MTb + (size_t)(j - 1) * MATF;

    const int tid = threadIdx.x;
    const int lane = tid & 63, wid = tid >> 6;
    const int rowBase = blockIdx.y * 128, colBase = blockIdx.x * 128;
    const int wr = (wid >> 1) * 64, wc = (wid & 1) * 64;

    int rowq[4], skq[4], ldsb[4];
#pragma unroll
    for (int q = 0; q < 4; ++q) {
        int c = q * 256 + wid * 64 + lane;
        int row = c >> 3;
        rowq[q] = row;
        skq[q] = ((c ^ (row & 7)) & 7) << 3;
        ldsb[q] = (q * 256 + wid * 64) << 4;
    }

    f32x4 acc[4][4];
#pragma unroll
    for (int a = 0; a < 4; ++a)
#pragma unroll
        for (int b = 0; b < 4; ++b) acc[a][b] = (f32x4){0.f, 0.f, 0.f, 0.f};

    auto stage = [&](int k0) {
#pragma unroll
        for (int q = 0; q < 4; ++q) {
            GLD16(Zt + (size_t)(rowBase + rowq[q]) * DD + k0 + skq[q], pool + ldsb[q]);
            GLD16(MT + (size_t)(colBase + rowq[q]) * DD + k0 + skq[q],
                  pool + 16384 + ldsb[q]);
        }
    };

    stage(0);
    for (int r = 0; r < 4; ++r) {
        __syncthreads();
        const char* asb = pool;
        const char* bsb = pool + 16384;
#pragma unroll
        for (int ks = 0; ks < 2; ++ks) {
            bf16x8 af[4], bg[4];
            const int kk = ks * 32 + (lane >> 4) * 8;
#pragma unroll
            for (int f = 0; f < 4; ++f) {
                int rr = wr + f * 16 + (lane & 15);
                af[f] = *(const bf16x8*)(asb + ((rr * 128 + kk * 2) ^ ((rr & 7) << 4)));
                int cc = wc + f * 16 + (lane & 15);
                bg[f] = *(const bf16x8*)(bsb + ((cc * 128 + kk * 2) ^ ((cc & 7) << 4)));
            }
#pragma unroll
            for (int fr = 0; fr < 4; ++fr)
#pragma unroll
                for (int fc = 0; fc < 4; ++fc)
                    acc[fr][fc] = __builtin_amdgcn_mfma_f32_16x16x32_bf16(
                        af[fr], bg[fc], acc[fr][fc], 0, 0, 0);
        }
        __syncthreads();
        if (r < 3) stage((r + 1) * 64);
    }

    float* Cs = (float*)pool;
    float* C = out + (size_t)t * DD;
#pragma unroll
    for (int hp = 0; hp < 2; ++hp) {
        __syncthreads();
        if (wr == hp * 64) {
#pragma unroll
            for (int fr = 0; fr < 4; ++fr) {
#pragma unroll
                for (int fc = 0; fc < 4; ++fc) {
                    int ccol = wc + fc * 16 + (lane & 15);
#pragma unroll
                    for (int ii = 0; ii < 4; ++ii) {
                        int lr = fr * 16 + ((lane >> 4) << 2) + ii;
                        int csw = ccol ^ (((lr >> 2) & 1) << 4);
                        Cs[lr * 128 + csw] = acc[fr][fc][ii];
                    }
                }
            }
        }
        __syncthreads();
#pragma unroll
        for (int it = 0; it < 8; ++it) {
            int chunk = it * 256 + tid;
            int row = chunk >> 5;
            int c4 = (chunk & 31) << 2;
            int csw = c4 ^ (((row >> 2) & 1) << 4);
            float4 v = *(const float4*)(Cs + row * 128 + csw);
            *(float4*)(C + (size_t)(rowBase + hp * 64 + row) * LDT + colBase + c4) = v;
        }
    }
}

// ---------------- fallback (tiny ws): proven g32 chain ----------------------
__global__ void prep_kernel(const float* __restrict__ K,
                            const float* __restrict__ log_dt,
                            float* __restrict__ A) {
    int idx = blockIdx.x * blockDim.x + threadIdx.x;
    A[idx] = 0.5f * expf(log_dt[0]) * K[idx];
}

template <int EPI>
__global__ void __launch_bounds__(256)
g32_kernel(const float* A, const float* B, float* C, const float* E, float* C2,
           int lda, int ldb, int ldc, long long sA, long long sB, long long sC) {
    float acc[2][2];
    const int rowBase = blockIdx.y << 5, colBase = blockIdx.x << 5;
    g32_core(A + blockIdx.z * sA, lda, B + blockIdx.z * sB, ldb, rowBase, colBase, acc);
    float* Cb = C + blockIdx.z * sC;
    const int r0 = rowBase + ((threadIdx.x >> 4) << 1);
    const int c0 = colBase + ((threadIdx.x & 15) << 1);
#pragma unroll
    for (int i = 0; i < 2; ++i) {
        int r = r0 + i;
        float2 v;
        if (EPI == 2) {
            float e0 = E[(size_t)r * DD + c0], e1 = E[(size_t)r * DD + c0 + 1];
            v.x = acc[i][0] + 2.f * e0 + (r == c0 ? 1.f : 0.f);
            v.y = acc[i][1] + 2.f * e1 + (r == c0 + 1 ? 1.f : 0.f);
        } else {
            v.x = acc[i][0];
            v.y = acc[i][1];
        }
        *(float2*)(Cb + (size_t)r * ldc + c0) = v;
        if (EPI == 1) {
            float e0 = E[(size_t)r * DD + c0], e1 = E[(size_t)r * DD + c0 + 1];
            float2 w;
            w.x = 2.f * acc[i][0] + 2.f * e0 + (r == c0 ? 2.f : 0.f);
            w.y = 2.f * acc[i][1] + 2.f * e1 + (r == c0 + 1 ? 2.f : 0.f);
            *(float2*)(C2 + (size_t)r * DD + c0) = w;
        }
    }
}

// ---------------- launch ----------------------------------------------------
extern "C" void kernel_launch(void* const* d_in, const int* in_sizes, int n_in,
                              void* d_out, int out_size, void* d_ws, size_t ws_size,
                              hipStream_t stream) {
    const float* z0 = (const float*)d_in[0];
    const float* Kmat = (const float*)d_in[1];
    const float* log_dt = (const float*)d_in[2];
    float* out = (float*)d_out;

    dim3 blk(256);

    // ws: Pw[8] (K..K^8) | W1 | W2 | W3 | Wtab[3] | Zf[16] f32
    //     | MTb[32] | Zb[16] bf16
    float* Pw = (float*)d_ws;
    float* W1 = Pw + (size_t)8 * MATF;
    float* W2 = W1 + MATF;
    float* W3 = W2 + MATF;
    float* Wtab = W3 + MATF;
    float* Zf = Wtab + (size_t)3 * MATF;
    unsigned short* MTb = (unsigned short*)(Zf + (size_t)16 * MATF);
    unsigned short* Zb = MTb + (size_t)32 * MATF;
    const size_t need = (size_t)30 * MATF * 4 + (size_t)48 * MATF * 2;

    if (ws_size >= need) {
        dim3 g(8, 8, 1);
        // K-powers: K^2 ; {K^3 = K@K^2, K^4 = K^2@K^2} ; {K^5..K^8}
        p1_kernel<<<g, blk, 0, stream>>>(Kmat, Pw);
        gpow_kernel<<<dim3(8, 8, 2), blk, 0, stream>>>(
            Pw, Pw + MATF, Pw + 2 * (size_t)MATF, MATF, 0, MATF);
        gpow4_kernel<<<dim3(8, 8, 4), blk, 0, stream>>>(Pw);

        // All 32 M-tables (bf16-T) + W1/W2/W3 f32 + bf16(z0), one launch
        comb_kernel<<<g, blk, 0, stream>>>(Pw, log_dt, z0, MTb, W1, W2, W3, Zb);

        // checkpoint scan: 3 batched levels, contiguous operands
        const int njobs[3] = {5, 7, 6};
        for (int s = 0; s < 3; ++s)
            scan3_kernel<<<dim3(8, 8, njobs[s]), blk, 0, stream>>>(
                z0, Zf, W1, W2, W3, Wtab, Zb, s);

        // ALL 512 timesteps, j-major order
        fill_kernel<<<dim3(2, 2, 512), blk, 0, stream>>>(Zb, MTb, out);
        return;
    }

    // Minimal fallback (tiny ws): Kd then 512 chained GEMMs (f32, proven core).
    float* A = (float*)d_ws;
    float* A2f = A + MATF;
    float* Bopf = A2f + MATF;
    float* Kd = Bopf + MATF;
    prep_kernel<<<MATF / 256, blk, 0, stream>>>(Kmat, log_dt, A);
    dim3 g(8, 8, 1);
    g32_kernel<1><<<g, blk, 0, stream>>>(A, A, A2f, A, Bopf, DD, DD, DD, 0, 0, 0);
    g32_kernel<2><<<g, blk, 0, stream>>>(A2f, Bopf, Kd, A, (float*)0, DD, DD, DD, 0, 0, 0);
    for (int t = 0; t < TT; ++t) {
        const float* Ain = (t == 0) ? z0 : out + (size_t)(t - 1) * DD;
        int lda = (t == 0) ? DD : (int)LDT;
        g32_kernel<0><<<g, blk, 0, stream>>>(Ain, Kd, out + (size_t)t * DD,
                                             (const float*)0, (float*)0,
                                             lda, DD, (int)LDT, 0, 0, 0);
    }
}

// Round 15
// 96.675 us; speedup vs baseline: 1.2915x; 1.0689x over previous
//
#include <hip/hip_runtime.h>

// Koopman bilinear rollout: preds[b,t,d] = (z0 @ Kd^{t+1})[b,d], D=B=256, T=512.
// r15: direct K-power series (r14) + 2-LEVEL scan:
//   M_j = I + sum_{m<=8} g_m^(j) cs^m K^m ; comb also emits W1..W5 =
//   Kd^{32,64,96,128,160} f32 (order-8, W5 trunc ~2e-4 rel) + bf16(z0).
//   L0: Z1..Z5 = z0@W1..5, W10 = W5@W5 ; L1: Z6..10 = Z1..5@W5,
//   Z11..15 = Z1..5@W10. Chain: p1,g2,g3,comb,L0,L1,fill = 6 dependent stages.
// Truncation: M_j rel ~1e-10, W5 ~2e-4 -> <0.2 abs on outputs (2.0 bf16 floor).
// DEAD ENDS (do not retry): persistent kernel + grid barrier (r5 392us,
// r7 289us); 256x256 fill tile (r11, -5us); fill j-major ~neutral (r13).
// Budget model (r14): ~5-6us per dependent stage, fill ~25-30us.

#define DD 256
#define TT 512
#define MATF (DD * DD)
#define LDT ((size_t)TT * (size_t)DD)

typedef __attribute__((ext_vector_type(8))) short bf16x8;
typedef __attribute__((ext_vector_type(4))) float f32x4;

#define GLD16(g, l)                                                  \
    __builtin_amdgcn_global_load_lds(                                \
        (const __attribute__((address_space(1))) void*)(g),          \
        (__attribute__((address_space(3))) void*)(l), 16, 0, 0)

static __device__ __forceinline__ unsigned short f2bf(float f) {
    unsigned int u = __float_as_uint(f);
    u += 0x7fffu + ((u >> 16) & 1u);
    return (unsigned short)(u >> 16);
}
static __device__ __forceinline__ unsigned pack2bf(float a, float b) {
    return (unsigned)f2bf(a) | ((unsigned)f2bf(b) << 16);
}

// ---- 32x32-tile f32 GEMM core: 256 threads, K=256, K_BLK=64, reg prefetch ----
__device__ __forceinline__ void g32_core(const float* __restrict__ Ab, int lda,
                                         const float* __restrict__ Bb, int ldb,
                                         int rowBase, int colBase, float acc[2][2]) {
    __shared__ __align__(16) float As[64 * 38];
    __shared__ __align__(16) float Bs[64 * 40];
    const int tid = threadIdx.x;
    const int tx = tid & 15, ty = tid >> 4;
    const int am = tid >> 4;
    const int ak = (tid & 15) << 2;
    const int bk = tid >> 3;
    const int bn = (tid & 7) << 2;

    acc[0][0] = acc[0][1] = acc[1][0] = acc[1][1] = 0.f;

    float4 pa0 = *(const float4*)(Ab + (size_t)(rowBase + am) * lda + ak);
    float4 pa1 = *(const float4*)(Ab + (size_t)(rowBase + am + 16) * lda + ak);
    float4 pb0 = *(const float4*)(Bb + (size_t)bk * ldb + colBase + bn);
    float4 pb1 = *(const float4*)(Bb + (size_t)(bk + 32) * ldb + colBase + bn);

    for (int k0 = 0; k0 < DD; k0 += 64) {
        As[(ak + 0) * 38 + am] = pa0.x;
        As[(ak + 1) * 38 + am] = pa0.y;
        As[(ak + 2) * 38 + am] = pa0.z;
        As[(ak + 3) * 38 + am] = pa0.w;
        As[(ak + 0) * 38 + am + 16] = pa1.x;
        As[(ak + 1) * 38 + am + 16] = pa1.y;
        As[(ak + 2) * 38 + am + 16] = pa1.z;
        As[(ak + 3) * 38 + am + 16] = pa1.w;
        *(float4*)(&Bs[bk * 40 + bn]) = pb0;
        *(float4*)(&Bs[(bk + 32) * 40 + bn]) = pb1;
        __syncthreads();
        if (k0 + 64 < DD) {
            pa0 = *(const float4*)(Ab + (size_t)(rowBase + am) * lda + k0 + 64 + ak);
            pa1 = *(const float4*)(Ab + (size_t)(rowBase + am + 16) * lda + k0 + 64 + ak);
            pb0 = *(const float4*)(Bb + (size_t)(bk + k0 + 64) * ldb + colBase + bn);
            pb1 = *(const float4*)(Bb + (size_t)(bk + 32 + k0 + 64) * ldb + colBase + bn);
        }
#pragma unroll
        for (int kk = 0; kk < 64; ++kk) {
            float2 a2 = *(const float2*)(&As[kk * 38 + (ty << 1)]);
            float2 b2 = *(const float2*)(&Bs[kk * 40 + (tx << 1)]);
            acc[0][0] = fmaf(a2.x, b2.x, acc[0][0]);
            acc[0][1] = fmaf(a2.x, b2.y, acc[0][1]);
            acc[1][0] = fmaf(a2.y, b2.x, acc[1][0]);
            acc[1][1] = fmaf(a2.y, b2.y, acc[1][1]);
        }
        __syncthreads();
    }
}

// p1: Pw[0] = K (copy) ; Pw[1] = K@K
__global__ void __launch_bounds__(256)
p1_kernel(const float* __restrict__ K, float* __restrict__ Pw) {
    {
        int b = ((blockIdx.y * 8 + blockIdx.x) * 256 + threadIdx.x) * 4;
        *(float4*)(Pw + b) = *(const float4*)(K + b);
    }
    float acc[2][2];
    const int rowBase = blockIdx.y << 5, colBase = blockIdx.x << 5;
    g32_core(K, DD, K, DD, rowBase, colBase, acc);
    float* Cb = Pw + MATF;
    const int r0 = rowBase + ((threadIdx.x >> 4) << 1);
    const int c0 = colBase + ((threadIdx.x & 15) << 1);
#pragma unroll
    for (int i = 0; i < 2; ++i) {
        int r = r0 + i;
        *(float2*)(Cb + (size_t)r * DD + c0) = (float2){acc[i][0], acc[i][1]};
    }
}

// stage 2 (batch 2): K^3 = K@K^2, K^4 = K^2@K^2
__global__ void __launch_bounds__(256)
gpow_kernel(const float* __restrict__ A, const float* __restrict__ B,
            float* __restrict__ C, long long sA, long long sB, long long sC) {
    float acc[2][2];
    const int rowBase = blockIdx.y << 5, colBase = blockIdx.x << 5;
    g32_core(A + blockIdx.z * sA, DD, B + blockIdx.z * sB, DD, rowBase, colBase, acc);
    float* Cb = C + blockIdx.z * sC;
    const int r0 = rowBase + ((threadIdx.x >> 4) << 1);
    const int c0 = colBase + ((threadIdx.x & 15) << 1);
#pragma unroll
    for (int i = 0; i < 2; ++i) {
        int r = r0 + i;
        *(float2*)(Cb + (size_t)r * DD + c0) = (float2){acc[i][0], acc[i][1]};
    }
}

// stage 3 (batch 4): K^5=K^2@K^3, K^6=K^3@K^3, K^7=K^3@K^4, K^8=K^4@K^4
__global__ void __launch_bounds__(256)
gpow4_kernel(float* __restrict__ Pw) {
    static const int sa[4] = {1, 2, 2, 3};
    static const int sb[4] = {2, 2, 3, 3};
    static const int sc[4] = {4, 5, 6, 7};
    const int z = blockIdx.z;
    float acc[2][2];
    const int rowBase = blockIdx.y << 5, colBase = blockIdx.x << 5;
    g32_core(Pw + (size_t)sa[z] * MATF, DD, Pw + (size_t)sb[z] * MATF, DD,
             rowBase, colBase, acc);
    float* Cb = Pw + (size_t)sc[z] * MATF;
    const int r0 = rowBase + ((threadIdx.x >> 4) << 1);
    const int c0 = colBase + ((threadIdx.x & 15) << 1);
#pragma unroll
    for (int i = 0; i < 2; ++i) {
        int r = r0 + i;
        *(float2*)(Cb + (size_t)r * DD + c0) = (float2){acc[i][0], acc[i][1]};
    }
}

// comb: M_j = I + sum_{m=1..8} g_m^(j) cs^m K^m (j=1..32) -> bf16 MTb[j][c][k]
// + f32 W1..W5 = Kd^{32,64,96,128,160} + Zb0 = bf16(z0).
// g_m^(j) = sum_p C(j,p) C(j+m-p-1, m-p), exact in double (max ~3e15 < 2^53).
__global__ void __launch_bounds__(256)
comb_kernel(const float* __restrict__ Pw, const float* __restrict__ log_dt,
            const float* __restrict__ z0, unsigned short* __restrict__ MTb,
            float* __restrict__ W1, float* __restrict__ W2,
            float* __restrict__ W3, float* __restrict__ W4,
            float* __restrict__ W5, unsigned short* __restrict__ Zb0) {
    __shared__ float tle[8][32][33];
    __shared__ float gtab[36][8];
    const int tid = threadIdx.x;
    const int k0 = blockIdx.y << 5, c0 = blockIdx.x << 5;
    const float csf = 0.5f * expf(log_dt[0]);

    // fold prep: bf16(z0), 4 elems/thread
    {
        int b = ((blockIdx.y * 8 + blockIdx.x) * 256 + tid) * 4;
        uint2 w;
        w.x = pack2bf(z0[b], z0[b + 1]);
        w.y = pack2bf(z0[b + 2], z0[b + 3]);
        *(uint2*)(Zb0 + b) = w;
    }

    // coefficient rows: 0..31 -> j=1..32 ; 32..35 -> j=64,96,128,160
    if (tid < 36) {
        int j = (tid < 32) ? (tid + 1) : (32 * (tid - 30));  // 64,96,128,160
        double b[9], cq[9];
        b[0] = 1.0;
        cq[0] = 1.0;
#pragma unroll
        for (int p = 1; p <= 8; ++p) {
            b[p] = b[p - 1] * (double)(j - p + 1) / (double)p;   // C(j,p)
            cq[p] = cq[p - 1] * (double)(j + p - 1) / (double)p; // C(j+p-1,p)
        }
        double csm = (double)csf;
#pragma unroll
        for (int m = 1; m <= 8; ++m) {
            double s = 0.0;
#pragma unroll
            for (int p = 0; p <= 8; ++p)
                if (p <= m) s += b[p] * cq[m - p];
            gtab[tid][m - 1] = (float)(s * csm);
            csm *= (double)csf;
        }
    }

    const int ltx = tid & 31, lty = tid >> 5;
#pragma unroll
    for (int m = 0; m < 8; ++m)
#pragma unroll
        for (int it = 0; it < 4; ++it) {
            int k = lty + (it << 3);
            tle[m][ltx][k] =
                Pw[(size_t)m * MATF + (size_t)(k0 + k) * DD + c0 + ltx];
        }
    __syncthreads();

    const int c = tid >> 3;
    const int kb = (tid & 7) << 2;
    float em[8][4];
#pragma unroll
    for (int m = 0; m < 8; ++m)
#pragma unroll
        for (int u = 0; u < 4; ++u) em[m][u] = tle[m][c][kb + u];

    float diag[4];
#pragma unroll
    for (int u = 0; u < 4; ++u)
        diag[u] = ((k0 + kb + u) == (c0 + c)) ? 1.f : 0.f;

    float w32[4];
    for (int j = 1; j <= 32; ++j) {
        float val[4] = {diag[0], diag[1], diag[2], diag[3]};
        const float* gj = gtab[j - 1];
#pragma unroll
        for (int m = 0; m < 8; ++m)
#pragma unroll
            for (int u = 0; u < 4; ++u) val[u] = fmaf(gj[m], em[m][u], val[u]);
        uint2 w;
        w.x = pack2bf(val[0], val[1]);
        w.y = pack2bf(val[2], val[3]);
        *(uint2*)(MTb + (size_t)(j - 1) * MATF + (size_t)(c0 + c) * DD + k0 + kb) = w;
        if (j == 32) {
            w32[0] = val[0]; w32[1] = val[1]; w32[2] = val[2]; w32[3] = val[3];
        }
    }
    float wv[4][4];
#pragma unroll
    for (int q = 0; q < 4; ++q)
#pragma unroll
        for (int u = 0; u < 4; ++u) wv[q][u] = diag[u];
#pragma unroll
    for (int m = 0; m < 8; ++m)
#pragma unroll
        for (int q = 0; q < 4; ++q)
#pragma unroll
            for (int u = 0; u < 4; ++u)
                wv[q][u] = fmaf(gtab[32 + q][m], em[m][u], wv[q][u]);

    // five LDS-transpose passes -> coalesced f32 stores in [k][c] layout
    float* tw = &tle[0][0][0];
    const int wk = tid >> 3, wc = (tid & 7) << 2;
    float* Wd[5] = {W1, W2, W3, W4, W5};
    float* Ws[5] = {w32, wv[0], wv[1], wv[2], wv[3]};
#pragma unroll
    for (int p = 0; p < 5; ++p) {
        __syncthreads();
#pragma unroll
        for (int u = 0; u < 4; ++u) tw[(kb + u) * 33 + c] = Ws[p][u];
        __syncthreads();
        float4 v = {tw[wk * 33 + wc], tw[wk * 33 + wc + 1],
                    tw[wk * 33 + wc + 2], tw[wk * 33 + wc + 3]};
        *(float4*)(Wd[p] + (size_t)(k0 + wk) * DD + c0 + wc) = v;
    }
}

// 2-level checkpoint scan, contiguous operands.
// a: 0=z0, 1..15=Zf[a], 16+k=Wp[k]; b: Wp index; d: 1..15=Z_dst, 19=Wtab (W10).
// Wp = {W1,W2,W3,W4,W5,W10}.
// L0 (6): Z1..Z5 = z0@W1..5 ; W10 = W5@W5.
// L1 (10): Z6..Z10 = Z1..5@W5 ; Z11..Z15 = Z1..5@W10.
__global__ void __launch_bounds__(256)
scan2_kernel(const float* __restrict__ z0, float* __restrict__ Zf,
             const float* __restrict__ W1, const float* __restrict__ W2,
             const float* __restrict__ W3, const float* __restrict__ W4,
             const float* __restrict__ W5, float* __restrict__ Wtab,
             unsigned short* __restrict__ Zb, int level) {
    static const signed char JA[2][10] = {
        {0, 0, 0, 0, 0, 20, 0, 0, 0, 0},
        {1, 2, 3, 4, 5, 1, 2, 3, 4, 5}};
    static const signed char JB[2][10] = {
        {0, 1, 2, 3, 4, 4, 0, 0, 0, 0},
        {4, 4, 4, 4, 4, 5, 5, 5, 5, 5}};
    static const signed char JD[2][10] = {
        {1, 2, 3, 4, 5, 19, 0, 0, 0, 0},
        {6, 7, 8, 9, 10, 11, 12, 13, 14, 15}};
    const float* Wp[6] = {W1, W2, W3, W4, W5, Wtab};
    const int jz = blockIdx.z;
    const int a = JA[level][jz], b = JB[level][jz], d = JD[level][jz];

    const float* Asrc;
    if (a == 0) Asrc = z0;
    else if (a < 16) Asrc = Zf + (size_t)a * MATF;
    else Asrc = Wp[a - 16];

    float acc[2][2];
    const int rowBase = blockIdx.y << 5, colBase = blockIdx.x << 5;
    g32_core(Asrc, DD, Wp[b], DD, rowBase, colBase, acc);

    const int r0 = rowBase + ((threadIdx.x >> 4) << 1);
    const int c0 = colBase + ((threadIdx.x & 15) << 1);
    if (d < 16) {
        float* Zo32 = Zf + (size_t)d * MATF;
        unsigned short* Zo = Zb + (size_t)d * MATF;
#pragma unroll
        for (int ii = 0; ii < 2; ++ii) {
            int r = r0 + ii;
            float2 v = {acc[ii][0], acc[ii][1]};
            *(float2*)(Zo32 + (size_t)r * DD + c0) = v;
            *(unsigned*)(Zo + (size_t)r * DD + c0) = pack2bf(v.x, v.y);
        }
    } else {
        float* Cb = Wtab;
#pragma unroll
        for (int ii = 0; ii < 2; ++ii) {
            int r = r0 + ii;
            *(float2*)(Cb + (size_t)r * DD + c0) = (float2){acc[ii][0], acc[ii][1]};
        }
    }
}

// Batched bf16 MFMA fill (proven r8/r10/r13), all 512 timesteps, j-major.
__global__ void __launch_bounds__(256)
fill_kernel(const unsigned short* __restrict__ Zb,
            const unsigned short* __restrict__ MTb,
            float* __restrict__ out) {
    __shared__ __align__(16) char pool[32768];
    const int zz = blockIdx.z;
    const int i = zz & 15;
    const int j = (zz >> 4) + 1;
    const int t = i * 32 + j - 1;
    const unsigned short* Zt = Zb + (size_t)i * MATF;
    const unsigned short* MT = MTb + (size_t)(j - 1) * MATF;

    const int tid = threadIdx.x;
    const int lane = tid & 63, wid = tid >> 6;
    const int rowBase = blockIdx.y * 128, colBase = blockIdx.x * 128;
    const int wr = (wid >> 1) * 64, wc = (wid & 1) * 64;

    int rowq[4], skq[4], ldsb[4];
#pragma unroll
    for (int q = 0; q < 4; ++q) {
        int c = q * 256 + wid * 64 + lane;
        int row = c >> 3;
        rowq[q] = row;
        skq[q] = ((c ^ (row & 7)) & 7) << 3;
        ldsb[q] = (q * 256 + wid * 64) << 4;
    }

    f32x4 acc[4][4];
#pragma unroll
    for (int a = 0; a < 4; ++a)
#pragma unroll
        for (int b = 0; b < 4; ++b) acc[a][b] = (f32x4){0.f, 0.f, 0.f, 0.f};

    auto stage = [&](int k0) {
#pragma unroll
        for (int q = 0; q < 4; ++q) {
            GLD16(Zt + (size_t)(rowBase + rowq[q]) * DD + k0 + skq[q], pool + ldsb[q]);
            GLD16(MT + (size_t)(colBase + rowq[q]) * DD + k0 + skq[q],
                  pool + 16384 + ldsb[q]);
        }
    };

    stage(0);
    for (int r = 0; r < 4; ++r) {
        __syncthreads();
        const char* asb = pool;
        const char* bsb = pool + 16384;
#pragma unroll
        for (int ks = 0; ks < 2; ++ks) {
            bf16x8 af[4], bg[4];
            const int kk = ks * 32 + (lane >> 4) * 8;
#pragma unroll
            for (int f = 0; f < 4; ++f) {
                int rr = wr + f * 16 + (lane & 15);
                af[f] = *(const bf16x8*)(asb + ((rr * 128 + kk * 2) ^ ((rr & 7) << 4)));
                int cc = wc + f * 16 + (lane & 15);
                bg[f] = *(const bf16x8*)(bsb + ((cc * 128 + kk * 2) ^ ((cc & 7) << 4)));
            }
#pragma unroll
            for (int fr = 0; fr < 4; ++fr)
#pragma unroll
                for (int fc = 0; fc < 4; ++fc)
                    acc[fr][fc] = __builtin_amdgcn_mfma_f32_16x16x32_bf16(
                        af[fr], bg[fc], acc[fr][fc], 0, 0, 0);
        }
        __syncthreads();
        if (r < 3) stage((r + 1) * 64);
    }

    float* Cs = (float*)pool;
    float* C = out + (size_t)t * DD;
#pragma unroll
    for (int hp = 0; hp < 2; ++hp) {
        __syncthreads();
        if (wr == hp * 64) {
#pragma unroll
            for (int fr = 0; fr < 4; ++fr) {
#pragma unroll
                for (int fc = 0; fc < 4; ++fc) {
                    int ccol = wc + fc * 16 + (lane & 15);
#pragma unroll
                    for (int ii = 0; ii < 4; ++ii) {
                        int lr = fr * 16 + ((lane >> 4) << 2) + ii;
                        int csw = ccol ^ (((lr >> 2) & 1) << 4);
                        Cs[lr * 128 + csw] = acc[fr][fc][ii];
                    }
                }
            }
        }
        __syncthreads();
#pragma unroll
        for (int it = 0; it < 8; ++it) {
            int chunk = it * 256 + tid;
            int row = chunk >> 5;
            int c4 = (chunk & 31) << 2;
            int csw = c4 ^ (((row >> 2) & 1) << 4);
            float4 v = *(const float4*)(Cs + row * 128 + csw);
            *(float4*)(C + (size_t)(rowBase + hp * 64 + row) * LDT + colBase + c4) = v;
        }
    }
}

// ---------------- fallback (tiny ws): proven g32 chain ----------------------
__global__ void prep_kernel(const float* __restrict__ K,
                            const float* __restrict__ log_dt,
                            float* __restrict__ A) {
    int idx = blockIdx.x * blockDim.x + threadIdx.x;
    A[idx] = 0.5f * expf(log_dt[0]) * K[idx];
}

template <int EPI>
__global__ void __launch_bounds__(256)
g32_kernel(const float* A, const float* B, float* C, const float* E, float* C2,
           int lda, int ldb, int ldc, long long sA, long long sB, long long sC) {
    float acc[2][2];
    const int rowBase = blockIdx.y << 5, colBase = blockIdx.x << 5;
    g32_core(A + blockIdx.z * sA, lda, B + blockIdx.z * sB, ldb, rowBase, colBase, acc);
    float* Cb = C + blockIdx.z * sC;
    const int r0 = rowBase + ((threadIdx.x >> 4) << 1);
    const int c0 = colBase + ((threadIdx.x & 15) << 1);
#pragma unroll
    for (int i = 0; i < 2; ++i) {
        int r = r0 + i;
        float2 v;
        if (EPI == 2) {
            float e0 = E[(size_t)r * DD + c0], e1 = E[(size_t)r * DD + c0 + 1];
            v.x = acc[i][0] + 2.f * e0 + (r == c0 ? 1.f : 0.f);
            v.y = acc[i][1] + 2.f * e1 + (r == c0 + 1 ? 1.f : 0.f);
        } else {
            v.x = acc[i][0];
            v.y = acc[i][1];
        }
        *(float2*)(Cb + (size_t)r * ldc + c0) = v;
        if (EPI == 1) {
            float e0 = E[(size_t)r * DD + c0], e1 = E[(size_t)r * DD + c0 + 1];
            float2 w;
            w.x = 2.f * acc[i][0] + 2.f * e0 + (r == c0 ? 2.f : 0.f);
            w.y = 2.f * acc[i][1] + 2.f * e1 + (r == c0 + 1 ? 2.f : 0.f);
            *(float2*)(C2 + (size_t)r * DD + c0) = w;
        }
    }
}

// ---------------- launch ----------------------------------------------------
extern "C" void kernel_launch(void* const* d_in, const int* in_sizes, int n_in,
                              void* d_out, int out_size, void* d_ws, size_t ws_size,
                              hipStream_t stream) {
    const float* z0 = (const float*)d_in[0];
    const float* Kmat = (const float*)d_in[1];
    const float* log_dt = (const float*)d_in[2];
    float* out = (float*)d_out;

    dim3 blk(256);

    // ws: Pw[8] (K..K^8) | W1..W5 | Wtab[1] (W10) | Zf[16] f32
    //     | MTb[32] | Zb[16] bf16
    float* Pw = (float*)d_ws;
    float* W1 = Pw + (size_t)8 * MATF;
    float* W2 = W1 + MATF;
    float* W3 = W2 + MATF;
    float* W4 = W3 + MATF;
    float* W5 = W4 + MATF;
    float* Wtab = W5 + MATF;
    float* Zf = Wtab + MATF;
    unsigned short* MTb = (unsigned short*)(Zf + (size_t)16 * MATF);
    unsigned short* Zb = MTb + (size_t)32 * MATF;
    const size_t need = (size_t)30 * MATF * 4 + (size_t)48 * MATF * 2;

    if (ws_size >= need) {
        dim3 g(8, 8, 1);
        // K-powers: K^2 ; {K^3, K^4} ; {K^5..K^8}
        p1_kernel<<<g, blk, 0, stream>>>(Kmat, Pw);
        gpow_kernel<<<dim3(8, 8, 2), blk, 0, stream>>>(
            Pw, Pw + MATF, Pw + 2 * (size_t)MATF, MATF, 0, MATF);
        gpow4_kernel<<<dim3(8, 8, 4), blk, 0, stream>>>(Pw);

        // All 32 M-tables (bf16-T) + W1..W5 f32 + bf16(z0), one launch
        comb_kernel<<<g, blk, 0, stream>>>(Pw, log_dt, z0, MTb, W1, W2, W3, W4,
                                           W5, Zb);

        // checkpoint scan: 2 batched levels
        scan2_kernel<<<dim3(8, 8, 6), blk, 0, stream>>>(z0, Zf, W1, W2, W3, W4,
                                                        W5, Wtab, Zb, 0);
        scan2_kernel<<<dim3(8, 8, 10), blk, 0, stream>>>(z0, Zf, W1, W2, W3, W4,
                                                         W5, Wtab, Zb, 1);

        // ALL 512 timesteps, j-major order
        fill_kernel<<<dim3(2, 2, 512), blk, 0, stream>>>(Zb, MTb, out);
        return;
    }

    // Minimal fallback (tiny ws): Kd then 512 chained GEMMs (f32, proven core).
    float* A = (float*)d_ws;
    float* A2f = A + MATF;
    float* Bopf = A2f + MATF;
    float* Kd = Bopf + MATF;
    prep_kernel<<<MATF / 256, blk, 0, stream>>>(Kmat, log_dt, A);
    dim3 g(8, 8, 1);
    g32_kernel<1><<<g, blk, 0, stream>>>(A, A, A2f, A, Bopf, DD, DD, DD, 0, 0, 0);
    g32_kernel<2><<<g, blk, 0, stream>>>(A2f, Bopf, Kd, A, (float*)0, DD, DD, DD, 0, 0, 0);
    for (int t = 0; t < TT; ++t) {
        const float* Ain = (t == 0) ? z0 : out + (size_t)(t - 1) * DD;
        int lda = (t == 0) ? DD : (int)LDT;
        g32_kernel<0><<<g, blk, 0, stream>>>(Ain, Kd, out + (size_t)t * DD,
                                             (const float*)0, (float*)0,
                                             lda, DD, (int)LDT, 0, 0, 0);
    }
}